// Round 13
// baseline (1346.905 us; speedup 1.0000x reference)
//
#include <hip/hip_runtime.h>

typedef __attribute__((ext_vector_type(8))) short bf16x8;
typedef __attribute__((ext_vector_type(4))) float f32x4;

#define N_TOK 4096
#define NC_ATT 8
#define NC_GEMM 8

// rpe quad-range split across the three fused kernels (QUADS = 4096*4096/4)
#define RPE_QUADS 4194304L
#define RPE_Q1 629145L   // 15%
#define RPE_Q2 3355443L  // 80%

// Diagnostic repetition factors (outputs identical; time = REP x base)
#define REP_K1 24
#define REP_K2 5
#define REP_K3 24
#define REP_GEMM 16
#define REP_TAIL 48

static __device__ __forceinline__ ushort f2bf(float f) {
    union { float f; unsigned u; } x; x.f = f;
    unsigned u = x.u;
    unsigned r = (u + 0x7FFFu + ((u >> 16) & 1u)) >> 16;
    return (ushort)r;
}
// HW packed f32x2 -> bf16x2 (RNE), lo = a, hi = b
static __device__ __forceinline__ unsigned pkbf(float a, float b) {
    unsigned r;
    asm("v_cvt_pk_bf16_f32 %0, %1, %2" : "=v"(r) : "v"(a), "v"(b));
    return r;
}
static __device__ __forceinline__ float bf2f(ushort u) {
    union { unsigned u; float f; } x; x.u = (unsigned)u << 16; return x.f;
}

// rpe streaming body: process quad range [lo, hi) with blocks of T threads
static __device__ __forceinline__ void rpe_stream_role(
    const float* __restrict__ rpe, const float* __restrict__ rpe_w,
    const float* __restrict__ rpe_b, ushort* __restrict__ rpeW,
    long lo, long hi, int rb, long stride) {
    float w0 = rpe_w[0], w1 = rpe_w[1], w2 = rpe_w[2], w3 = rpe_w[3], w4 = rpe_w[4];
    float bb = rpe_b[0];
    const float4* p = (const float4*)rpe;
    for (long i = lo + (long)rb * blockDim.x + threadIdx.x; i < hi; i += stride) {
        float4 a0 = p[i];
        float4 a1 = p[i + RPE_QUADS];
        float4 a2 = p[i + 2 * RPE_QUADS];
        float4 a3 = p[i + 3 * RPE_QUADS];
        float4 a4 = p[i + 4 * RPE_QUADS];
        ushort4 o;
        unsigned lov = pkbf(bb + w0 * a0.x + w1 * a1.x + w2 * a2.x + w3 * a3.x + w4 * a4.x,
                            bb + w0 * a0.y + w1 * a1.y + w2 * a2.y + w3 * a3.y + w4 * a4.y);
        unsigned hiv = pkbf(bb + w0 * a0.z + w1 * a1.z + w2 * a2.z + w3 * a3.z + w4 * a4.z,
                            bb + w0 * a0.w + w1 * a1.w + w2 * a2.w + w3 * a3.w + w4 * a4.w);
        o.x = (ushort)lov; o.y = (ushort)(lov >> 16);
        o.z = (ushort)hiv; o.w = (ushort)(hiv >> 16);
        ((ushort4*)rpeW)[i] = o;
    }
}

// ---------------- prep: cast x + all weight transposes in one kernel ------
__global__ void prep_all(const float* __restrict__ x,
                         const float* __restrict__ Wq, const float* __restrict__ Wk,
                         const float* __restrict__ Wv, const float* __restrict__ Wo,
                         const float* __restrict__ W1, const float* __restrict__ W2,
                         ushort* __restrict__ xb, ushort* __restrict__ WqT,
                         ushort* __restrict__ WkT, ushort* __restrict__ WvT,
                         ushort* __restrict__ WoT, ushort* __restrict__ W1T,
                         ushort* __restrict__ W2T) {
    int i = blockIdx.x * 256 + threadIdx.x;
    if (i < 131072) {  // x: 4096*128/4 quads
        float4 v = ((const float4*)x)[i];
        ushort4 o;
        o.x = f2bf(v.x); o.y = f2bf(v.y); o.z = f2bf(v.z); o.w = f2bf(v.w);
        ((ushort4*)xb)[i] = o;
        return;
    }
    int j = i - 131072;
    int t = j >> 15, e = j & 32767;
    if (t < 3) {  // Wq/Wk/Wv [4][128][64] -> [4][64][128]
        const float* src = (t == 0 ? Wq : t == 1 ? Wk : Wv);
        ushort* dst = (t == 0 ? WqT : t == 1 ? WkT : WvT);
        int h = e >> 13, rem = e & 8191, d = rem >> 6, k = rem & 63;
        dst[h * 8192 + k * 128 + d] = f2bf(src[e]);
    } else if (t == 3) {  // Wo [256][128] -> [128][256]
        int r = e >> 7, c = e & 127;
        WoT[c * 256 + r] = f2bf(Wo[e]);
    } else if (t == 4) {  // W1 [128][256] -> [256][128]
        int r = e >> 8, c = e & 255;
        W1T[c * 128 + r] = f2bf(W1[e]);
    } else {  // W2 [256][128] -> [128][256]
        int r = e >> 7, c = e & 127;
        W2T[c * 256 + r] = f2bf(W2[e]);
    }
}

// ---------------- K1: qkv (blocks 0..767) || rpe stream [0,15%) ------------
__global__ __launch_bounds__(256) void fused_rpe_qkv(
    const float* __restrict__ rpe, const float* __restrict__ rpe_w,
    const float* __restrict__ rpe_b, ushort* __restrict__ rpeW,
    const ushort* __restrict__ xb, const ushort* __restrict__ WqT,
    const ushort* __restrict__ WkT, const ushort* __restrict__ WvT,
    const float* __restrict__ bq, const float* __restrict__ bk, const float* __restrict__ bv,
    ushort* __restrict__ qb, ushort* __restrict__ kb, ushort* __restrict__ vT) {
    int bid = blockIdx.x;
    if (bid >= 768) {
#pragma unroll 1
        for (int rep = 0; rep < REP_K1; ++rep) {
            asm volatile("" ::: "memory");
            rpe_stream_role(rpe, rpe_w, rpe_b, rpeW, 0L, RPE_Q1, bid - 768, (long)1024 * 256);
        }
        return;
    }
    int m0 = (bid & 63) * 64;
    int y = bid >> 6;
    int h = y & 3, which = y >> 2;
    int wave = threadIdx.x >> 6, lane = threadIdx.x & 63;
    int fr = lane & 15, kg = lane >> 4;
    int wm = m0 + wave * 16;
    const ushort* WT = (which == 0 ? WqT : which == 1 ? WkT : WvT) + (long)h * 64 * 128;
    const float* bias = (which == 0 ? bq : which == 1 ? bk : bv) + h * 64;
#pragma unroll 1
    for (int rep = 0; rep < REP_K1; ++rep) {
        asm volatile("" ::: "memory");
        f32x4 acc[4] = {};
        for (int k0 = 0; k0 < 128; k0 += 32) {
            bf16x8 a = *(const bf16x8*)(xb + (long)(wm + fr) * 128 + k0 + kg * 8);
#pragma unroll
            for (int t = 0; t < 4; ++t) {
                bf16x8 b = *(const bf16x8*)(WT + (long)(t * 16 + fr) * 128 + k0 + kg * 8);
                acc[t] = __builtin_amdgcn_mfma_f32_16x16x32_bf16(a, b, acc[t], 0, 0, 0);
            }
        }
        int rb = wm + kg * 4;
#pragma unroll
        for (int t = 0; t < 4; ++t) {
            int col = t * 16 + fr;
            float bs = bias[col];
            if (which == 2) {
                ushort4 o;
                o.x = f2bf(fmaxf(acc[t][0] + bs, 0.f));
                o.y = f2bf(fmaxf(acc[t][1] + bs, 0.f));
                o.z = f2bf(fmaxf(acc[t][2] + bs, 0.f));
                o.w = f2bf(fmaxf(acc[t][3] + bs, 0.f));
                *(ushort4*)(vT + ((long)h * 64 + col) * N_TOK + rb) = o;
            } else {
                ushort* dst = (which == 0 ? qb : kb) + (long)h * N_TOK * 64;
                float scl = (which == 0) ? 0.125f * 1.44269504f : 1.0f;
#pragma unroll
                for (int r = 0; r < 4; ++r)
                    dst[(long)(rb + r) * 64 + col] = f2bf(fmaxf(acc[t][r] + bs, 0.f) * scl);
            }
        }
    }
}

// ---------------- K2: rpe stream [15%,80%) (even) || flash attn (odd) -------
__global__ __launch_bounds__(512, 6) void fused_rpe_attn(
    const float* __restrict__ rpe, const float* __restrict__ rpe_w,
    const float* __restrict__ rpe_b, ushort* __restrict__ rpeW,
    const ushort* __restrict__ qb, const ushort* __restrict__ kb,
    const ushort* __restrict__ vT, ushort* __restrict__ opart,
    float* __restrict__ mlpart) {
    __shared__ ushort Kt[2][64 * 64];
    __shared__ ushort Vt[2][64 * 64];
    __shared__ ushort Pl[8][16 * 64];
    int bid = blockIdx.x;
    int idx = bid >> 1;
    if ((bid & 1) == 0) {
#pragma unroll 1
        for (int rep = 0; rep < REP_K2; ++rep) {
            asm volatile("" ::: "memory");
            rpe_stream_role(rpe, rpe_w, rpe_b, rpeW, RPE_Q1, RPE_Q2, idx, (long)1024 * 512);
        }
        return;
    }
    // ---------------- attention role ----------------
    int qt = idx & 31, h = (idx >> 5) & 3, cz = idx >> 7;
    int w = threadIdx.x >> 6, lane = threadIdx.x & 63;
    int fr = lane & 15, kg = lane >> 4;
    int lr = lane >> 3, lc = lane & 7;
    int swz = (lc ^ (lr & 7)) * 8;
    const ushort* qh = qb + (long)h * N_TOK * 64;
    const ushort* kh = kb + (long)h * N_TOK * 64;
    const ushort* vh = vT + (long)h * 64 * N_TOK;
    int q0 = qt * 128 + w * 16;
    bf16x8 qf0 = *(const bf16x8*)(qh + (long)(q0 + fr) * 64 + kg * 8);
    bf16x8 qf1 = *(const bf16x8*)(qh + (long)(q0 + fr) * 64 + 32 + kg * 8);
    int nbase = cz * (N_TOK / NC_ATT);
    auto stage = [&](int buf, int s) {
        int n0 = nbase + s * 64;
        int row = w * 8 + lr;  // wave w stages rows w*8..w*8+7 (1 instr each)
        __builtin_amdgcn_global_load_lds(
            (const __attribute__((address_space(1))) unsigned int*)(kh + (long)(n0 + row) * 64 + swz),
            (__attribute__((address_space(3))) unsigned int*)(&Kt[buf][w * 512]), 16, 0, 0);
        __builtin_amdgcn_global_load_lds(
            (const __attribute__((address_space(1))) unsigned int*)(vh + (long)row * N_TOK + n0 + swz),
            (__attribute__((address_space(3))) unsigned int*)(&Vt[buf][w * 512]), 16, 0, 0);
    };
#pragma unroll 1
    for (int rep = 0; rep < REP_K2; ++rep) {
        asm volatile("" ::: "memory");
        __syncthreads();
        f32x4 o[4] = {};
        float lsum = 0.f;
        stage(0, 0);
        __syncthreads();
        const int NS = (N_TOK / NC_ATT) / 64;
        for (int s = 0; s < NS; ++s) {
            int buf = s & 1;
            if (s + 1 < NS) stage(buf ^ 1, s + 1);
            f32x4 sc[4] = {};
            __builtin_amdgcn_s_setprio(1);
#pragma unroll
            for (int t = 0; t < 4; ++t) {
                int row = t * 16 + fr;
                bf16x8 k0 = *(const bf16x8*)(&Kt[buf][row * 64 + ((kg * 8) ^ ((row & 7) * 8))]);
                bf16x8 k1 = *(const bf16x8*)(&Kt[buf][row * 64 + ((32 + kg * 8) ^ ((row & 7) * 8))]);
                sc[t] = __builtin_amdgcn_mfma_f32_16x16x32_bf16(k0, qf0, sc[t], 0, 0, 0);
                sc[t] = __builtin_amdgcn_mfma_f32_16x16x32_bf16(k1, qf1, sc[t], 0, 0, 0);
            }
            __builtin_amdgcn_s_setprio(0);
#pragma unroll
            for (int t = 0; t < 4; ++t)
#pragma unroll
                for (int r = 0; r < 4; ++r) {
                    float p = exp2f(sc[t][r]);
                    sc[t][r] = p;
                    lsum += p;
                }
#pragma unroll
            for (int t = 0; t < 4; ++t) {
                uint2 u;
                u.x = pkbf(sc[t][0], sc[t][1]);
                u.y = pkbf(sc[t][2], sc[t][3]);
                *(uint2*)(&Pl[w][fr * 64 + ((t * 16 + kg * 4) ^ ((fr & 7) * 8))]) = u;
            }
            __builtin_amdgcn_s_setprio(1);
#pragma unroll
            for (int ks = 0; ks < 2; ++ks) {
                bf16x8 pf = *(const bf16x8*)(&Pl[w][fr * 64 + ((ks * 32 + kg * 8) ^ ((fr & 7) * 8))]);
#pragma unroll
                for (int t = 0; t < 4; ++t) {
                    int row = t * 16 + fr;
                    bf16x8 b = *(const bf16x8*)(&Vt[buf][row * 64 + ((ks * 32 + kg * 8) ^ ((row & 7) * 8))]);
                    o[t] = __builtin_amdgcn_mfma_f32_16x16x32_bf16(pf, b, o[t], 0, 0, 0);
                }
            }
            __builtin_amdgcn_s_setprio(0);
            __syncthreads();
        }
        lsum += __shfl_xor(lsum, 16);
        lsum += __shfl_xor(lsum, 32);
        float linv = 1.0f / lsum;
        float lq[4];
#pragma unroll
        for (int r = 0; r < 4; ++r) lq[r] = __shfl(linv, kg * 4 + r);
        ushort* ob = opart + (((long)cz * 4 + h) * N_TOK + q0 + kg * 4) * 64;
#pragma unroll
        for (int t = 0; t < 4; ++t)
#pragma unroll
            for (int r = 0; r < 4; ++r)
                ob[(long)r * 64 + t * 16 + fr] = f2bf(o[t][r] * lq[r]);
        if (lane < 16)
            mlpart[((long)cz * 4 + h) * N_TOK + q0 + lane] = lsum;
    }
}

// ---------------- K3: combine+Wo (blocks 0..255) || rpe stream [80%,100%) ---
__global__ __launch_bounds__(256) void fused_rpe_cw(
    const float* __restrict__ rpe, const float* __restrict__ rpe_w,
    const float* __restrict__ rpe_b, ushort* __restrict__ rpeW,
    const ushort* __restrict__ opart, const float* __restrict__ mlpart,
    const ushort* __restrict__ WoT, ushort* __restrict__ PT) {
    int bid = blockIdx.x;
    if (bid >= 256) {
#pragma unroll 1
        for (int rep = 0; rep < REP_K3; ++rep) {
            asm volatile("" ::: "memory");
            rpe_stream_role(rpe, rpe_w, rpe_b, rpeW, RPE_Q2, RPE_QUADS, bid - 256, (long)768 * 256);
        }
        return;
    }
    int q0 = bid * 16;
    int tid = threadIdx.x;
    __shared__ ushort mt[16 * 256];
#pragma unroll 1
    for (int rep = 0; rep < REP_K3; ++rep) {
        asm volatile("" ::: "memory");
        __syncthreads();
        {
            int q = tid >> 4, cg = tid & 15;
            int h = cg >> 2;
            long qg = q0 + q;
            float L = 0.f, co[NC_ATT];
#pragma unroll
            for (int c = 0; c < NC_ATT; ++c) {
                co[c] = mlpart[((long)c * 4 + h) * N_TOK + qg];
                L += co[c];
            }
            float inv = 1.0f / L;
#pragma unroll
            for (int c = 0; c < NC_ATT; ++c) co[c] *= inv;
            float a[16];
#pragma unroll
            for (int j = 0; j < 16; ++j) a[j] = 0.f;
#pragma unroll
            for (int c = 0; c < NC_ATT; ++c) {
                const ushort* pr = opart + (((long)c * 4 + h) * N_TOK + qg) * 64 + (cg & 3) * 16;
                bf16x8 v0 = *(const bf16x8*)(pr);
                bf16x8 v1 = *(const bf16x8*)(pr + 8);
#pragma unroll
                for (int j = 0; j < 8; ++j) {
                    a[j] += co[c] * bf2f((ushort)v0[j]);
                    a[8 + j] += co[c] * bf2f((ushort)v1[j]);
                }
            }
            int c0 = cg * 16;
#pragma unroll
            for (int g = 0; g < 4; ++g) {
                uint2 u;
                u.x = pkbf(a[g * 4 + 0], a[g * 4 + 1]);
                u.y = pkbf(a[g * 4 + 2], a[g * 4 + 3]);
                *(uint2*)(&mt[q * 256 + ((c0 + g * 4) ^ ((q & 7) * 8))]) = u;
            }
        }
        __syncthreads();
        {
            int w = tid >> 6, lane = tid & 63;
            int fr = lane & 15, kg = lane >> 4;
            f32x4 acc[2] = {};
            for (int k0 = 0; k0 < 256; k0 += 32) {
                bf16x8 a0 = *(const bf16x8*)(WoT + (long)(w * 32 + fr) * 256 + k0 + kg * 8);
                bf16x8 a1 = *(const bf16x8*)(WoT + (long)(w * 32 + 16 + fr) * 256 + k0 + kg * 8);
                bf16x8 b = *(const bf16x8*)(&mt[fr * 256 + ((k0 + kg * 8) ^ ((fr & 7) * 8))]);
                acc[0] = __builtin_amdgcn_mfma_f32_16x16x32_bf16(a0, b, acc[0], 0, 0, 0);
                acc[1] = __builtin_amdgcn_mfma_f32_16x16x32_bf16(a1, b, acc[1], 0, 0, 0);
            }
#pragma unroll
            for (int dt = 0; dt < 2; ++dt)
#pragma unroll
                for (int r = 0; r < 4; ++r)
                    PT[(long)(w * 32 + dt * 16 + kg * 4 + r) * N_TOK + q0 + fr] =
                        f2bf(acc[dt][r]);
        }
    }
}

// ---------------- gemm2: part[c] = rpeW[.,Kc] @ PT^T (both bf16, gload_lds) -
__global__ __launch_bounds__(512) void gemm_big2(
    const ushort* __restrict__ A, const ushort* __restrict__ PT,
    float* __restrict__ part) {
    int mt = blockIdx.x, cz = blockIdx.y;
    int tid = threadIdx.x;
    int w = tid >> 6, lane = tid & 63;
    int fr = lane & 15, kg = lane >> 4;
    int lr = lane >> 3, lc = lane & 7;
    int swz = (lc ^ (lr & 7)) * 8;
    int ms = w >> 1, nh = w & 1;
    __shared__ ushort At[2][64 * 64];    // 16 KB
    __shared__ ushort Bt[2][128 * 64];   // 32 KB
    int m0 = mt * 64;
    long kbase = (long)cz * (N_TOK / NC_GEMM);
    int arow = ms * 16 + fr;
    auto stage = [&](int buf, int s) {
        long kc = kbase + s * 64 + swz;
        int rowA = w * 8 + lr;
        __builtin_amdgcn_global_load_lds(
            (const __attribute__((address_space(1))) unsigned int*)(A + (long)(m0 + rowA) * N_TOK + kc),
            (__attribute__((address_space(3))) unsigned int*)(&At[buf][w * 512]), 16, 0, 0);
#pragma unroll
        for (int j = 0; j < 2; ++j) {
            int row = w * 16 + j * 8 + lr;
            __builtin_amdgcn_global_load_lds(
                (const __attribute__((address_space(1))) unsigned int*)(PT + (long)row * N_TOK + kc),
                (__attribute__((address_space(3))) unsigned int*)(&Bt[buf][(w * 2 + j) * 512]), 16, 0, 0);
        }
    };
#pragma unroll 1
    for (int rep = 0; rep < REP_GEMM; ++rep) {
        asm volatile("" ::: "memory");
        __syncthreads();
        f32x4 acc[4] = {};
        stage(0, 0);
        __syncthreads();
        const int NS = (N_TOK / NC_GEMM) / 64;
        for (int s = 0; s < NS; ++s) {
            int buf = s & 1;
            if (s + 1 < NS) stage(buf ^ 1, s + 1);
            __builtin_amdgcn_s_setprio(1);
#pragma unroll
            for (int ks = 0; ks < 2; ++ks) {
                int c = ks * 32 + kg * 8;
                bf16x8 av = *(const bf16x8*)(&At[buf][arow * 64 + (c ^ ((arow & 7) * 8))]);
#pragma unroll
                for (int nf = 0; nf < 4; ++nf) {
                    int row = nh * 64 + nf * 16 + fr;
                    bf16x8 b = *(const bf16x8*)(&Bt[buf][row * 64 + (c ^ ((row & 7) * 8))]);
                    acc[nf] = __builtin_amdgcn_mfma_f32_16x16x32_bf16(av, b, acc[nf], 0, 0, 0);
                }
            }
            __builtin_amdgcn_s_setprio(0);
            __syncthreads();
        }
        float* pb = part + ((long)cz * N_TOK + m0 + ms * 16 + kg * 4) * 128 + nh * 64 + fr;
#pragma unroll
        for (int nf = 0; nf < 4; ++nf)
#pragma unroll
            for (int r = 0; r < 4; ++r)
                pb[(long)r * 128 + nf * 16] = acc[nf][r];
    }
}

// ---------------- megatail: sum parts + bo + x -> LN1 -> FFN -> LN2 -> out --
__global__ __launch_bounds__(256) void megatail(
    const float* __restrict__ gpart, const float* __restrict__ bo,
    const float* __restrict__ x, const float* __restrict__ g1,
    const float* __restrict__ lb1, const ushort* __restrict__ W1T,
    const float* __restrict__ b1, const ushort* __restrict__ W2T,
    const float* __restrict__ b2, const float* __restrict__ g2,
    const float* __restrict__ lb2, float* __restrict__ out) {
    int r0 = blockIdx.x * 16;
    int tid = threadIdx.x;
    int w = tid >> 6, lane = tid & 63;
    int fr = lane & 15, kg = lane >> 4;
    __shared__ float x1f[16][132];
    __shared__ ushort x1b[16][128];
    __shared__ ushort hbuf[16][256];
    __shared__ float otile[16][132];
    int row = tid >> 4, c0 = (tid & 15) * 8;
#pragma unroll 1
    for (int rep = 0; rep < REP_TAIL; ++rep) {
        asm volatile("" ::: "memory");
        __syncthreads();
        {
            float v[8];
            float4 s0 = {0.f, 0.f, 0.f, 0.f}, s1 = {0.f, 0.f, 0.f, 0.f};
#pragma unroll
            for (int c = 0; c < NC_GEMM; ++c) {
                const float* pr = gpart + ((long)c * N_TOK + r0 + row) * 128 + c0;
                float4 a = *(const float4*)(pr);
                float4 b = *(const float4*)(pr + 4);
                s0.x += a.x; s0.y += a.y; s0.z += a.z; s0.w += a.w;
                s1.x += b.x; s1.y += b.y; s1.z += b.z; s1.w += b.w;
            }
            const float* xr = x + (long)(r0 + row) * 128 + c0;
            v[0] = s0.x + bo[c0 + 0] + xr[0];
            v[1] = s0.y + bo[c0 + 1] + xr[1];
            v[2] = s0.z + bo[c0 + 2] + xr[2];
            v[3] = s0.w + bo[c0 + 3] + xr[3];
            v[4] = s1.x + bo[c0 + 4] + xr[4];
            v[5] = s1.y + bo[c0 + 5] + xr[5];
            v[6] = s1.z + bo[c0 + 6] + xr[6];
            v[7] = s1.w + bo[c0 + 7] + xr[7];
            float s = 0.f;
#pragma unroll
            for (int jj = 0; jj < 8; ++jj) s += v[jj];
#pragma unroll
            for (int off = 1; off < 16; off <<= 1) s += __shfl_xor(s, off);
            float mean = s * (1.0f / 128.0f);
            float ss = 0.f;
#pragma unroll
            for (int jj = 0; jj < 8; ++jj) { float d = v[jj] - mean; ss += d * d; }
#pragma unroll
            for (int off = 1; off < 16; off <<= 1) ss += __shfl_xor(ss, off);
            float rstd = rsqrtf(ss * (1.0f / 128.0f) + 1e-5f);
            union { bf16x8 vec; ushort us[8]; } pk8;
#pragma unroll
            for (int jj = 0; jj < 8; ++jj) {
                float y = (v[jj] - mean) * rstd * g1[c0 + jj] + lb1[c0 + jj];
                x1f[row][c0 + jj] = y;
                pk8.us[jj] = f2bf(y);
            }
            *(bf16x8*)(&x1b[row][c0 ^ ((row & 7) * 8)]) = pk8.vec;
        }
        __syncthreads();
        {
            f32x4 a1[4] = {};
#pragma unroll
            for (int ks = 0; ks < 4; ++ks) {
                bf16x8 a = *(const bf16x8*)(&x1b[fr][(ks * 32 + kg * 8) ^ ((fr & 7) * 8)]);
#pragma unroll
                for (int t = 0; t < 4; ++t) {
                    bf16x8 b = *(const bf16x8*)(W1T + (long)(w * 64 + t * 16 + fr) * 128 + ks * 32 + kg * 8);
                    a1[t] = __builtin_amdgcn_mfma_f32_16x16x32_bf16(a, b, a1[t], 0, 0, 0);
                }
            }
#pragma unroll
            for (int t = 0; t < 4; ++t) {
                int col = w * 64 + t * 16 + fr;
                float bs = b1[col];
#pragma unroll
                for (int r = 0; r < 4; ++r) {
                    int rr = kg * 4 + r;
                    hbuf[rr][col ^ ((rr & 7) * 8)] = f2bf(fmaxf(a1[t][r] + bs, 0.f));
                }
            }
        }
        __syncthreads();
        {
            f32x4 a2[2] = {};
#pragma unroll
            for (int ks = 0; ks < 8; ++ks) {
                bf16x8 a = *(const bf16x8*)(&hbuf[fr][(ks * 32 + kg * 8) ^ ((fr & 7) * 8)]);
#pragma unroll
                for (int t = 0; t < 2; ++t) {
                    bf16x8 b = *(const bf16x8*)(W2T + (long)(w * 32 + t * 16 + fr) * 256 + ks * 32 + kg * 8);
                    a2[t] = __builtin_amdgcn_mfma_f32_16x16x32_bf16(a, b, a2[t], 0, 0, 0);
                }
            }
#pragma unroll
            for (int t = 0; t < 2; ++t) {
                int col = w * 32 + t * 16 + fr;
                float bs = b2[col];
#pragma unroll
                for (int r = 0; r < 4; ++r) {
                    int rr = kg * 4 + r;
                    otile[rr][col] = a2[t][r] + bs + x1f[rr][col];
                }
            }
        }
        __syncthreads();
        {
            float v[8];
            float s = 0.f;
#pragma unroll
            for (int jj = 0; jj < 8; ++jj) { v[jj] = otile[row][c0 + jj]; s += v[jj]; }
#pragma unroll
            for (int off = 1; off < 16; off <<= 1) s += __shfl_xor(s, off);
            float mean = s * (1.0f / 128.0f);
            float ss = 0.f;
#pragma unroll
            for (int jj = 0; jj < 8; ++jj) { float d = v[jj] - mean; ss += d * d; }
#pragma unroll
            for (int off = 1; off < 16; off <<= 1) ss += __shfl_xor(ss, off);
            float rstd = rsqrtf(ss * (1.0f / 128.0f) + 1e-5f);
#pragma unroll
            for (int jj = 0; jj < 8; ++jj) {
                float y = (v[jj] - mean) * rstd * g2[c0 + jj] + lb2[c0 + jj];
                out[(long)(r0 + row) * 128 + c0 + jj] = y;
            }
        }
    }
}

extern "C" void kernel_launch(void* const* d_in, const int* in_sizes, int n_in,
                              void* d_out, int out_size, void* d_ws, size_t ws_size,
                              hipStream_t stream) {
    const float* x     = (const float*)d_in[0];
    const float* rpe   = (const float*)d_in[1];
    const float* Wq    = (const float*)d_in[2];
    const float* bq    = (const float*)d_in[3];
    const float* Wk    = (const float*)d_in[4];
    const float* bk    = (const float*)d_in[5];
    const float* Wv    = (const float*)d_in[6];
    const float* bv    = (const float*)d_in[7];
    const float* rpe_w = (const float*)d_in[8];
    const float* rpe_b = (const float*)d_in[9];
    const float* Wo    = (const float*)d_in[10];
    const float* bo    = (const float*)d_in[11];
    const float* W1    = (const float*)d_in[12];
    const float* b1    = (const float*)d_in[13];
    const float* W2    = (const float*)d_in[14];
    const float* b2    = (const float*)d_in[15];
    const float* g1    = (const float*)d_in[16];
    const float* lb1   = (const float*)d_in[17];
    const float* g2    = (const float*)d_in[18];
    const float* lb2   = (const float*)d_in[19];

    char* wp = (char*)d_ws;
    auto alloc = [&](size_t sz) { char* p = wp; wp += (sz + 255) & ~(size_t)255; return p; };
    ushort* xb    = (ushort*)alloc((size_t)4096 * 128 * 2);
    ushort* WqT   = (ushort*)alloc((size_t)4 * 64 * 128 * 2);
    ushort* WkT   = (ushort*)alloc((size_t)4 * 64 * 128 * 2);
    ushort* WvT   = (ushort*)alloc((size_t)4 * 64 * 128 * 2);
    ushort* WoT   = (ushort*)alloc((size_t)128 * 256 * 2);
    ushort* W1T   = (ushort*)alloc((size_t)256 * 128 * 2);
    ushort* W2T   = (ushort*)alloc((size_t)128 * 256 * 2);
    ushort* qb    = (ushort*)alloc((size_t)4 * 4096 * 64 * 2);
    ushort* kbuf  = (ushort*)alloc((size_t)4 * 4096 * 64 * 2);
    ushort* vT    = (ushort*)alloc((size_t)4 * 64 * 4096 * 2);
    ushort* rpeW  = (ushort*)alloc((size_t)4096 * 4096 * 2);
    ushort* PTb   = (ushort*)alloc((size_t)128 * 4096 * 2);
    ushort* opart = (ushort*)alloc((size_t)NC_ATT * 4 * 4096 * 64 * 2);
    float*  mlprt = (float*)alloc((size_t)NC_ATT * 4 * 4096 * 4);
    float*  gpart = (float*)alloc((size_t)NC_GEMM * 4096 * 128 * 4);

    prep_all<<<1280, 256, 0, stream>>>(x, Wq, Wk, Wv, Wo, W1, W2,
                                       xb, WqT, WkT, WvT, WoT, W1T, W2T);
    fused_rpe_qkv<<<1792, 256, 0, stream>>>(rpe, rpe_w, rpe_b, rpeW,
                                            xb, WqT, WkT, WvT, bq, bk, bv, qb, kbuf, vT);
    fused_rpe_attn<<<2048, 512, 0, stream>>>(rpe, rpe_w, rpe_b, rpeW,
                                             qb, kbuf, vT, opart, mlprt);
    fused_rpe_cw<<<1024, 256, 0, stream>>>(rpe, rpe_w, rpe_b, rpeW,
                                           opart, mlprt, WoT, PTb);
    gemm_big2<<<dim3(64, NC_GEMM), 512, 0, stream>>>(rpeW, PTb, gpart);
    megatail<<<256, 256, 0, stream>>>(gpart, bo, x, g1, lb1, W1T, b1, W2T, b2,
                                      g2, lb2, (float*)d_out);
}

// Round 15
// 138.614 us; speedup vs baseline: 9.7170x; 9.7170x over previous
//
#include <hip/hip_runtime.h>

typedef __attribute__((ext_vector_type(8))) short bf16x8;
typedef __attribute__((ext_vector_type(4))) float f32x4;
typedef __attribute__((ext_vector_type(4))) unsigned short u16x4;

#define N_TOK 4096
#define NC_ATT 8
#define NC_GEMM 8

// rpe quad-range split across the three fused kernels (QUADS = 4096*4096/4)
#define RPE_QUADS 4194304L
#define RPE_Q1 1048576L  // 25% -> K1
#define RPE_Q2 2936013L  // 70% -> K2 gets 45%, K3 gets 30%

static __device__ __forceinline__ ushort f2bf(float f) {
    union { float f; unsigned u; } x; x.f = f;
    unsigned u = x.u;
    unsigned r = (u + 0x7FFFu + ((u >> 16) & 1u)) >> 16;
    return (ushort)r;
}
// HW packed f32x2 -> bf16x2 (RNE), lo = a, hi = b
static __device__ __forceinline__ unsigned pkbf(float a, float b) {
    unsigned r;
    asm("v_cvt_pk_bf16_f32 %0, %1, %2" : "=v"(r) : "v"(a), "v"(b));
    return r;
}
static __device__ __forceinline__ float bf2f(ushort u) {
    union { unsigned u; float f; } x; x.u = (unsigned)u << 16; return x.f;
}

// rpe streaming body with NON-TEMPORAL loads/stores: zero-reuse data must not
// evict attention's L2-resident K/V (the R13-measured +30us interference).
static __device__ __forceinline__ void rpe_stream_role(
    const float* __restrict__ rpe, const float* __restrict__ rpe_w,
    const float* __restrict__ rpe_b, ushort* __restrict__ rpeW,
    long lo, long hi, int rb, long stride) {
    float w0 = rpe_w[0], w1 = rpe_w[1], w2 = rpe_w[2], w3 = rpe_w[3], w4 = rpe_w[4];
    float bb = rpe_b[0];
    const f32x4* p = (const f32x4*)rpe;
    for (long i = lo + (long)rb * blockDim.x + threadIdx.x; i < hi; i += stride) {
        f32x4 a0 = __builtin_nontemporal_load(p + i);
        f32x4 a1 = __builtin_nontemporal_load(p + i + RPE_QUADS);
        f32x4 a2 = __builtin_nontemporal_load(p + i + 2 * RPE_QUADS);
        f32x4 a3 = __builtin_nontemporal_load(p + i + 3 * RPE_QUADS);
        f32x4 a4 = __builtin_nontemporal_load(p + i + 4 * RPE_QUADS);
        unsigned lov = pkbf(bb + w0 * a0.x + w1 * a1.x + w2 * a2.x + w3 * a3.x + w4 * a4.x,
                            bb + w0 * a0.y + w1 * a1.y + w2 * a2.y + w3 * a3.y + w4 * a4.y);
        unsigned hiv = pkbf(bb + w0 * a0.z + w1 * a1.z + w2 * a2.z + w3 * a3.z + w4 * a4.z,
                            bb + w0 * a0.w + w1 * a1.w + w2 * a2.w + w3 * a3.w + w4 * a4.w);
        u16x4 o;
        o.x = (ushort)lov; o.y = (ushort)(lov >> 16);
        o.z = (ushort)hiv; o.w = (ushort)(hiv >> 16);
        __builtin_nontemporal_store(o, ((u16x4*)rpeW) + i);
    }
}

// ---------------- prep: cast x + all weight transposes in one kernel ------
__global__ void prep_all(const float* __restrict__ x,
                         const float* __restrict__ Wq, const float* __restrict__ Wk,
                         const float* __restrict__ Wv, const float* __restrict__ Wo,
                         const float* __restrict__ W1, const float* __restrict__ W2,
                         ushort* __restrict__ xb, ushort* __restrict__ WqT,
                         ushort* __restrict__ WkT, ushort* __restrict__ WvT,
                         ushort* __restrict__ WoT, ushort* __restrict__ W1T,
                         ushort* __restrict__ W2T) {
    int i = blockIdx.x * 256 + threadIdx.x;
    if (i < 131072) {  // x: 4096*128/4 quads
        float4 v = ((const float4*)x)[i];
        ushort4 o;
        o.x = f2bf(v.x); o.y = f2bf(v.y); o.z = f2bf(v.z); o.w = f2bf(v.w);
        ((ushort4*)xb)[i] = o;
        return;
    }
    int j = i - 131072;
    int t = j >> 15, e = j & 32767;
    if (t < 3) {  // Wq/Wk/Wv [4][128][64] -> [4][64][128]
        const float* src = (t == 0 ? Wq : t == 1 ? Wk : Wv);
        ushort* dst = (t == 0 ? WqT : t == 1 ? WkT : WvT);
        int h = e >> 13, rem = e & 8191, d = rem >> 6, k = rem & 63;
        dst[h * 8192 + k * 128 + d] = f2bf(src[e]);
    } else if (t == 3) {  // Wo [256][128] -> [128][256]
        int r = e >> 7, c = e & 127;
        WoT[c * 256 + r] = f2bf(Wo[e]);
    } else if (t == 4) {  // W1 [128][256] -> [256][128]
        int r = e >> 8, c = e & 255;
        W1T[c * 128 + r] = f2bf(W1[e]);
    } else {  // W2 [256][128] -> [128][256]
        int r = e >> 7, c = e & 127;
        W2T[c * 256 + r] = f2bf(W2[e]);
    }
}

// ---------------- K1: qkv (blocks 0..767) || rpe stream [0,25%) ------------
__global__ __launch_bounds__(256) void fused_rpe_qkv(
    const float* __restrict__ rpe, const float* __restrict__ rpe_w,
    const float* __restrict__ rpe_b, ushort* __restrict__ rpeW,
    const ushort* __restrict__ xb, const ushort* __restrict__ WqT,
    const ushort* __restrict__ WkT, const ushort* __restrict__ WvT,
    const float* __restrict__ bq, const float* __restrict__ bk, const float* __restrict__ bv,
    ushort* __restrict__ qb, ushort* __restrict__ kb, ushort* __restrict__ vT) {
    int bid = blockIdx.x;
    if (bid >= 768) {
        rpe_stream_role(rpe, rpe_w, rpe_b, rpeW, 0L, RPE_Q1, bid - 768, (long)1024 * 256);
        return;
    }
    int m0 = (bid & 63) * 64;
    int y = bid >> 6;
    int h = y & 3, which = y >> 2;
    int wave = threadIdx.x >> 6, lane = threadIdx.x & 63;
    int fr = lane & 15, kg = lane >> 4;
    int wm = m0 + wave * 16;
    const ushort* WT = (which == 0 ? WqT : which == 1 ? WkT : WvT) + (long)h * 64 * 128;
    const float* bias = (which == 0 ? bq : which == 1 ? bk : bv) + h * 64;
    f32x4 acc[4] = {};
    for (int k0 = 0; k0 < 128; k0 += 32) {
        bf16x8 a = *(const bf16x8*)(xb + (long)(wm + fr) * 128 + k0 + kg * 8);
#pragma unroll
        for (int t = 0; t < 4; ++t) {
            bf16x8 b = *(const bf16x8*)(WT + (long)(t * 16 + fr) * 128 + k0 + kg * 8);
            acc[t] = __builtin_amdgcn_mfma_f32_16x16x32_bf16(a, b, acc[t], 0, 0, 0);
        }
    }
    int rb = wm + kg * 4;
#pragma unroll
    for (int t = 0; t < 4; ++t) {
        int col = t * 16 + fr;
        float bs = bias[col];
        if (which == 2) {
            ushort4 o;
            o.x = f2bf(fmaxf(acc[t][0] + bs, 0.f));
            o.y = f2bf(fmaxf(acc[t][1] + bs, 0.f));
            o.z = f2bf(fmaxf(acc[t][2] + bs, 0.f));
            o.w = f2bf(fmaxf(acc[t][3] + bs, 0.f));
            *(ushort4*)(vT + ((long)h * 64 + col) * N_TOK + rb) = o;
        } else {
            ushort* dst = (which == 0 ? qb : kb) + (long)h * N_TOK * 64;
            float scl = (which == 0) ? 0.125f * 1.44269504f : 1.0f;
#pragma unroll
            for (int r = 0; r < 4; ++r)
                dst[(long)(rb + r) * 64 + col] = f2bf(fmaxf(acc[t][r] + bs, 0.f) * scl);
        }
    }
}

// ---------------- K2: rpe stream [25%,70%) (even) || flash attn (odd) -------
__global__ __launch_bounds__(512, 6) void fused_rpe_attn(
    const float* __restrict__ rpe, const float* __restrict__ rpe_w,
    const float* __restrict__ rpe_b, ushort* __restrict__ rpeW,
    const ushort* __restrict__ qb, const ushort* __restrict__ kb,
    const ushort* __restrict__ vT, ushort* __restrict__ opart,
    float* __restrict__ mlpart) {
    __shared__ ushort Kt[2][64 * 64];
    __shared__ ushort Vt[2][64 * 64];
    __shared__ ushort Pl[8][16 * 64];
    int bid = blockIdx.x;
    int idx = bid >> 1;
    if ((bid & 1) == 0) {
        rpe_stream_role(rpe, rpe_w, rpe_b, rpeW, RPE_Q1, RPE_Q2, idx, (long)1024 * 512);
        return;
    }
    // ---------------- attention role ----------------
    int qt = idx & 31, h = (idx >> 5) & 3, cz = idx >> 7;
    int w = threadIdx.x >> 6, lane = threadIdx.x & 63;
    int fr = lane & 15, kg = lane >> 4;
    int lr = lane >> 3, lc = lane & 7;
    int swz = (lc ^ (lr & 7)) * 8;
    const ushort* qh = qb + (long)h * N_TOK * 64;
    const ushort* kh = kb + (long)h * N_TOK * 64;
    const ushort* vh = vT + (long)h * 64 * N_TOK;
    int q0 = qt * 128 + w * 16;
    bf16x8 qf0 = *(const bf16x8*)(qh + (long)(q0 + fr) * 64 + kg * 8);
    bf16x8 qf1 = *(const bf16x8*)(qh + (long)(q0 + fr) * 64 + 32 + kg * 8);
    f32x4 o[4] = {};
    float lsum = 0.f;
    int nbase = cz * (N_TOK / NC_ATT);
    auto stage = [&](int buf, int s) {
        int n0 = nbase + s * 64;
        int row = w * 8 + lr;  // wave w stages rows w*8..w*8+7 (1 instr each)
        __builtin_amdgcn_global_load_lds(
            (const __attribute__((address_space(1))) unsigned int*)(kh + (long)(n0 + row) * 64 + swz),
            (__attribute__((address_space(3))) unsigned int*)(&Kt[buf][w * 512]), 16, 0, 0);
        __builtin_amdgcn_global_load_lds(
            (const __attribute__((address_space(1))) unsigned int*)(vh + (long)row * N_TOK + n0 + swz),
            (__attribute__((address_space(3))) unsigned int*)(&Vt[buf][w * 512]), 16, 0, 0);
    };
    stage(0, 0);
    __syncthreads();
    const int NS = (N_TOK / NC_ATT) / 64;
    for (int s = 0; s < NS; ++s) {
        int buf = s & 1;
        if (s + 1 < NS) stage(buf ^ 1, s + 1);
        // S^T = K @ Q^T: lane holds kv = t*16+kg*4+r for q = q0+fr
        f32x4 sc[4] = {};
        __builtin_amdgcn_s_setprio(1);
#pragma unroll
        for (int t = 0; t < 4; ++t) {
            int row = t * 16 + fr;
            bf16x8 k0 = *(const bf16x8*)(&Kt[buf][row * 64 + ((kg * 8) ^ ((row & 7) * 8))]);
            bf16x8 k1 = *(const bf16x8*)(&Kt[buf][row * 64 + ((32 + kg * 8) ^ ((row & 7) * 8))]);
            sc[t] = __builtin_amdgcn_mfma_f32_16x16x32_bf16(k0, qf0, sc[t], 0, 0, 0);
            sc[t] = __builtin_amdgcn_mfma_f32_16x16x32_bf16(k1, qf1, sc[t], 0, 0, 0);
        }
        __builtin_amdgcn_s_setprio(0);
#pragma unroll
        for (int t = 0; t < 4; ++t)
#pragma unroll
            for (int r = 0; r < 4; ++r) {
                float p = exp2f(sc[t][r]);
                sc[t][r] = p;
                lsum += p;
            }
#pragma unroll
        for (int t = 0; t < 4; ++t) {
            uint2 u;
            u.x = pkbf(sc[t][0], sc[t][1]);
            u.y = pkbf(sc[t][2], sc[t][3]);
            *(uint2*)(&Pl[w][fr * 64 + ((t * 16 + kg * 4) ^ ((fr & 7) * 8))]) = u;
        }
        __builtin_amdgcn_s_setprio(1);
#pragma unroll
        for (int ks = 0; ks < 2; ++ks) {
            bf16x8 pf = *(const bf16x8*)(&Pl[w][fr * 64 + ((ks * 32 + kg * 8) ^ ((fr & 7) * 8))]);
#pragma unroll
            for (int t = 0; t < 4; ++t) {
                int row = t * 16 + fr;
                bf16x8 b = *(const bf16x8*)(&Vt[buf][row * 64 + ((ks * 32 + kg * 8) ^ ((row & 7) * 8))]);
                o[t] = __builtin_amdgcn_mfma_f32_16x16x32_bf16(pf, b, o[t], 0, 0, 0);
            }
        }
        __builtin_amdgcn_s_setprio(0);
        __syncthreads();
    }
    // row sum for q=fr lives across lanes {fr, fr+16, fr+32, fr+48}
    lsum += __shfl_xor(lsum, 16);
    lsum += __shfl_xor(lsum, 32);
    float linv = 1.0f / lsum;
    float lq[4];
#pragma unroll
    for (int r = 0; r < 4; ++r) lq[r] = __shfl(linv, kg * 4 + r);
    ushort* ob = opart + (((long)cz * 4 + h) * N_TOK + q0 + kg * 4) * 64;
#pragma unroll
    for (int t = 0; t < 4; ++t)
#pragma unroll
        for (int r = 0; r < 4; ++r)
            ob[(long)r * 64 + t * 16 + fr] = f2bf(o[t][r] * lq[r]);
    if (lane < 16)
        mlpart[((long)cz * 4 + h) * N_TOK + q0 + lane] = lsum;
}

// ---------------- K3: combine+Wo (blocks 0..255) || rpe stream [70%,100%) ---
__global__ __launch_bounds__(256) void fused_rpe_cw(
    const float* __restrict__ rpe, const float* __restrict__ rpe_w,
    const float* __restrict__ rpe_b, ushort* __restrict__ rpeW,
    const ushort* __restrict__ opart, const float* __restrict__ mlpart,
    const ushort* __restrict__ WoT, ushort* __restrict__ PT) {
    int bid = blockIdx.x;
    if (bid >= 256) {
        rpe_stream_role(rpe, rpe_w, rpe_b, rpeW, RPE_Q2, RPE_QUADS, bid - 256, (long)768 * 256);
        return;
    }
    int q0 = bid * 16;
    int tid = threadIdx.x;
    __shared__ ushort mt[16 * 256];
    {
        int q = tid >> 4, cg = tid & 15;  // 16 rows x 16 col-groups (16 cols each)
        int h = cg >> 2;                  // head for this 16-col group
        long qg = q0 + q;
        float L = 0.f, co[NC_ATT];
#pragma unroll
        for (int c = 0; c < NC_ATT; ++c) {
            co[c] = mlpart[((long)c * 4 + h) * N_TOK + qg];
            L += co[c];
        }
        float inv = 1.0f / L;
#pragma unroll
        for (int c = 0; c < NC_ATT; ++c) co[c] *= inv;
        float a[16];
#pragma unroll
        for (int j = 0; j < 16; ++j) a[j] = 0.f;
#pragma unroll
        for (int c = 0; c < NC_ATT; ++c) {
            const ushort* pr = opart + (((long)c * 4 + h) * N_TOK + qg) * 64 + (cg & 3) * 16;
            bf16x8 v0 = *(const bf16x8*)(pr);
            bf16x8 v1 = *(const bf16x8*)(pr + 8);
#pragma unroll
            for (int j = 0; j < 8; ++j) {
                a[j] += co[c] * bf2f((ushort)v0[j]);
                a[8 + j] += co[c] * bf2f((ushort)v1[j]);
            }
        }
        int c0 = cg * 16;
#pragma unroll
        for (int g = 0; g < 4; ++g) {
            uint2 u;
            u.x = pkbf(a[g * 4 + 0], a[g * 4 + 1]);
            u.y = pkbf(a[g * 4 + 2], a[g * 4 + 3]);
            *(uint2*)(&mt[q * 256 + ((c0 + g * 4) ^ ((q & 7) * 8))]) = u;
        }
    }
    __syncthreads();
    {
        int w = tid >> 6, lane = tid & 63;
        int fr = lane & 15, kg = lane >> 4;
        f32x4 acc[2] = {};
        for (int k0 = 0; k0 < 256; k0 += 32) {
            bf16x8 a0 = *(const bf16x8*)(WoT + (long)(w * 32 + fr) * 256 + k0 + kg * 8);
            bf16x8 a1 = *(const bf16x8*)(WoT + (long)(w * 32 + 16 + fr) * 256 + k0 + kg * 8);
            bf16x8 b = *(const bf16x8*)(&mt[fr * 256 + ((k0 + kg * 8) ^ ((fr & 7) * 8))]);
            acc[0] = __builtin_amdgcn_mfma_f32_16x16x32_bf16(a0, b, acc[0], 0, 0, 0);
            acc[1] = __builtin_amdgcn_mfma_f32_16x16x32_bf16(a1, b, acc[1], 0, 0, 0);
        }
#pragma unroll
        for (int dt = 0; dt < 2; ++dt)
#pragma unroll
            for (int r = 0; r < 4; ++r)
                PT[(long)(w * 32 + dt * 16 + kg * 4 + r) * N_TOK + q0 + fr] =
                    f2bf(acc[dt][r]);
    }
}

// ---------------- gemm2: part[c] = rpeW[.,Kc] @ PT^T (both bf16, gload_lds) -
__global__ __launch_bounds__(512) void gemm_big2(
    const ushort* __restrict__ A, const ushort* __restrict__ PT,
    float* __restrict__ part) {
    int mt = blockIdx.x, cz = blockIdx.y;
    int tid = threadIdx.x;
    int w = tid >> 6, lane = tid & 63;
    int fr = lane & 15, kg = lane >> 4;
    int lr = lane >> 3, lc = lane & 7;
    int swz = (lc ^ (lr & 7)) * 8;
    int ms = w >> 1, nh = w & 1;
    __shared__ ushort At[2][64 * 64];    // 16 KB
    __shared__ ushort Bt[2][128 * 64];   // 32 KB
    int m0 = mt * 64;
    long kbase = (long)cz * (N_TOK / NC_GEMM);
    int arow = ms * 16 + fr;
    auto stage = [&](int buf, int s) {
        long kc = kbase + s * 64 + swz;
        int rowA = w * 8 + lr;
        __builtin_amdgcn_global_load_lds(
            (const __attribute__((address_space(1))) unsigned int*)(A + (long)(m0 + rowA) * N_TOK + kc),
            (__attribute__((address_space(3))) unsigned int*)(&At[buf][w * 512]), 16, 0, 0);
#pragma unroll
        for (int j = 0; j < 2; ++j) {
            int row = w * 16 + j * 8 + lr;
            __builtin_amdgcn_global_load_lds(
                (const __attribute__((address_space(1))) unsigned int*)(PT + (long)row * N_TOK + kc),
                (__attribute__((address_space(3))) unsigned int*)(&Bt[buf][(w * 2 + j) * 512]), 16, 0, 0);
        }
    };
    f32x4 acc[4] = {};
    stage(0, 0);
    __syncthreads();
    const int NS = (N_TOK / NC_GEMM) / 64;
    for (int s = 0; s < NS; ++s) {
        int buf = s & 1;
        if (s + 1 < NS) stage(buf ^ 1, s + 1);
        __builtin_amdgcn_s_setprio(1);
#pragma unroll
        for (int ks = 0; ks < 2; ++ks) {
            int c = ks * 32 + kg * 8;
            bf16x8 av = *(const bf16x8*)(&At[buf][arow * 64 + (c ^ ((arow & 7) * 8))]);
#pragma unroll
            for (int nf = 0; nf < 4; ++nf) {
                int row = nh * 64 + nf * 16 + fr;
                bf16x8 b = *(const bf16x8*)(&Bt[buf][row * 64 + (c ^ ((row & 7) * 8))]);
                acc[nf] = __builtin_amdgcn_mfma_f32_16x16x32_bf16(av, b, acc[nf], 0, 0, 0);
            }
        }
        __builtin_amdgcn_s_setprio(0);
        __syncthreads();
    }
    float* pb = part + ((long)cz * N_TOK + m0 + ms * 16 + kg * 4) * 128 + nh * 64 + fr;
#pragma unroll
    for (int nf = 0; nf < 4; ++nf)
#pragma unroll
        for (int r = 0; r < 4; ++r)
            pb[(long)r * 128 + nf * 16] = acc[nf][r];
}

// ---------------- megatail: sum parts + bo + x -> LN1 -> FFN -> LN2 -> out --
__global__ __launch_bounds__(256) void megatail(
    const float* __restrict__ gpart, const float* __restrict__ bo,
    const float* __restrict__ x, const float* __restrict__ g1,
    const float* __restrict__ lb1, const ushort* __restrict__ W1T,
    const float* __restrict__ b1, const ushort* __restrict__ W2T,
    const float* __restrict__ b2, const float* __restrict__ g2,
    const float* __restrict__ lb2, float* __restrict__ out) {
    int r0 = blockIdx.x * 16;
    int tid = threadIdx.x;
    int w = tid >> 6, lane = tid & 63;
    int fr = lane & 15, kg = lane >> 4;
    __shared__ float x1f[16][132];
    __shared__ ushort x1b[16][128];
    __shared__ ushort hbuf[16][256];
    __shared__ float otile[16][132];
    int row = tid >> 4, c0 = (tid & 15) * 8;
    {
        float v[8];
        float4 s0 = {0.f, 0.f, 0.f, 0.f}, s1 = {0.f, 0.f, 0.f, 0.f};
#pragma unroll
        for (int c = 0; c < NC_GEMM; ++c) {
            const float* pr = gpart + ((long)c * N_TOK + r0 + row) * 128 + c0;
            float4 a = *(const float4*)(pr);
            float4 b = *(const float4*)(pr + 4);
            s0.x += a.x; s0.y += a.y; s0.z += a.z; s0.w += a.w;
            s1.x += b.x; s1.y += b.y; s1.z += b.z; s1.w += b.w;
        }
        const float* xr = x + (long)(r0 + row) * 128 + c0;
        v[0] = s0.x + bo[c0 + 0] + xr[0];
        v[1] = s0.y + bo[c0 + 1] + xr[1];
        v[2] = s0.z + bo[c0 + 2] + xr[2];
        v[3] = s0.w + bo[c0 + 3] + xr[3];
        v[4] = s1.x + bo[c0 + 4] + xr[4];
        v[5] = s1.y + bo[c0 + 5] + xr[5];
        v[6] = s1.z + bo[c0 + 6] + xr[6];
        v[7] = s1.w + bo[c0 + 7] + xr[7];
        float s = 0.f;
#pragma unroll
        for (int jj = 0; jj < 8; ++jj) s += v[jj];
#pragma unroll
        for (int off = 1; off < 16; off <<= 1) s += __shfl_xor(s, off);
        float mean = s * (1.0f / 128.0f);
        float ss = 0.f;
#pragma unroll
        for (int jj = 0; jj < 8; ++jj) { float d = v[jj] - mean; ss += d * d; }
#pragma unroll
        for (int off = 1; off < 16; off <<= 1) ss += __shfl_xor(ss, off);
        float rstd = rsqrtf(ss * (1.0f / 128.0f) + 1e-5f);
        union { bf16x8 vec; ushort us[8]; } pk8;
#pragma unroll
        for (int jj = 0; jj < 8; ++jj) {
            float y = (v[jj] - mean) * rstd * g1[c0 + jj] + lb1[c0 + jj];
            x1f[row][c0 + jj] = y;
            pk8.us[jj] = f2bf(y);
        }
        *(bf16x8*)(&x1b[row][c0 ^ ((row & 7) * 8)]) = pk8.vec;
    }
    __syncthreads();
    {
        f32x4 a1[4] = {};
#pragma unroll
        for (int ks = 0; ks < 4; ++ks) {
            bf16x8 a = *(const bf16x8*)(&x1b[fr][(ks * 32 + kg * 8) ^ ((fr & 7) * 8)]);
#pragma unroll
            for (int t = 0; t < 4; ++t) {
                bf16x8 b = *(const bf16x8*)(W1T + (long)(w * 64 + t * 16 + fr) * 128 + ks * 32 + kg * 8);
                a1[t] = __builtin_amdgcn_mfma_f32_16x16x32_bf16(a, b, a1[t], 0, 0, 0);
            }
        }
#pragma unroll
        for (int t = 0; t < 4; ++t) {
            int col = w * 64 + t * 16 + fr;
            float bs = b1[col];
#pragma unroll
            for (int r = 0; r < 4; ++r) {
                int rr = kg * 4 + r;
                hbuf[rr][col ^ ((rr & 7) * 8)] = f2bf(fmaxf(a1[t][r] + bs, 0.f));
            }
        }
    }
    __syncthreads();
    {
        f32x4 a2[2] = {};
#pragma unroll
        for (int ks = 0; ks < 8; ++ks) {
            bf16x8 a = *(const bf16x8*)(&hbuf[fr][(ks * 32 + kg * 8) ^ ((fr & 7) * 8)]);
#pragma unroll
            for (int t = 0; t < 2; ++t) {
                bf16x8 b = *(const bf16x8*)(W2T + (long)(w * 32 + t * 16 + fr) * 256 + ks * 32 + kg * 8);
                a2[t] = __builtin_amdgcn_mfma_f32_16x16x32_bf16(a, b, a2[t], 0, 0, 0);
            }
        }
#pragma unroll
        for (int t = 0; t < 2; ++t) {
            int col = w * 32 + t * 16 + fr;
            float bs = b2[col];
#pragma unroll
            for (int r = 0; r < 4; ++r) {
                int rr = kg * 4 + r;
                otile[rr][col] = a2[t][r] + bs + x1f[rr][col];
            }
        }
    }
    __syncthreads();
    {
        float v[8];
        float s = 0.f;
#pragma unroll
        for (int jj = 0; jj < 8; ++jj) { v[jj] = otile[row][c0 + jj]; s += v[jj]; }
#pragma unroll
        for (int off = 1; off < 16; off <<= 1) s += __shfl_xor(s, off);
        float mean = s * (1.0f / 128.0f);
        float ss = 0.f;
#pragma unroll
        for (int jj = 0; jj < 8; ++jj) { float d = v[jj] - mean; ss += d * d; }
#pragma unroll
        for (int off = 1; off < 16; off <<= 1) ss += __shfl_xor(ss, off);
        float rstd = rsqrtf(ss * (1.0f / 128.0f) + 1e-5f);
#pragma unroll
        for (int jj = 0; jj < 8; ++jj) {
            float y = (v[jj] - mean) * rstd * g2[c0 + jj] + lb2[c0 + jj];
            out[(long)(r0 + row) * 128 + c0 + jj] = y;
        }
    }
}

extern "C" void kernel_launch(void* const* d_in, const int* in_sizes, int n_in,
                              void* d_out, int out_size, void* d_ws, size_t ws_size,
                              hipStream_t stream) {
    const float* x     = (const float*)d_in[0];
    const float* rpe   = (const float*)d_in[1];
    const float* Wq    = (const float*)d_in[2];
    const float* bq    = (const float*)d_in[3];
    const float* Wk    = (const float*)d_in[4];
    const float* bk    = (const float*)d_in[5];
    const float* Wv    = (const float*)d_in[6];
    const float* bv    = (const float*)d_in[7];
    const float* rpe_w = (const float*)d_in[8];
    const float* rpe_b = (const float*)d_in[9];
    const float* Wo    = (const float*)d_in[10];
    const float* bo    = (const float*)d_in[11];
    const float* W1    = (const float*)d_in[12];
    const float* b1    = (const float*)d_in[13];
    const float* W2    = (const float*)d_in[14];
    const float* b2    = (const float*)d_in[15];
    const float* g1    = (const float*)d_in[16];
    const float* lb1   = (const float*)d_in[17];
    const float* g2    = (const float*)d_in[18];
    const float* lb2   = (const float*)d_in[19];

    char* wp = (char*)d_ws;
    auto alloc = [&](size_t sz) { char* p = wp; wp += (sz + 255) & ~(size_t)255; return p; };
    ushort* xb    = (ushort*)alloc((size_t)4096 * 128 * 2);
    ushort* WqT   = (ushort*)alloc((size_t)4 * 64 * 128 * 2);
    ushort* WkT   = (ushort*)alloc((size_t)4 * 64 * 128 * 2);
    ushort* WvT   = (ushort*)alloc((size_t)4 * 64 * 128 * 2);
    ushort* WoT   = (ushort*)alloc((size_t)128 * 256 * 2);
    ushort* W1T   = (ushort*)alloc((size_t)256 * 128 * 2);
    ushort* W2T   = (ushort*)alloc((size_t)128 * 256 * 2);
    ushort* qb    = (ushort*)alloc((size_t)4 * 4096 * 64 * 2);
    ushort* kbuf  = (ushort*)alloc((size_t)4 * 4096 * 64 * 2);
    ushort* vT    = (ushort*)alloc((size_t)4 * 64 * 4096 * 2);
    ushort* rpeW  = (ushort*)alloc((size_t)4096 * 4096 * 2);
    ushort* PTb   = (ushort*)alloc((size_t)128 * 4096 * 2);
    ushort* opart = (ushort*)alloc((size_t)NC_ATT * 4 * 4096 * 64 * 2);
    float*  mlprt = (float*)alloc((size_t)NC_ATT * 4 * 4096 * 4);
    float*  gpart = (float*)alloc((size_t)NC_GEMM * 4096 * 128 * 4);

    prep_all<<<1280, 256, 0, stream>>>(x, Wq, Wk, Wv, Wo, W1, W2,
                                       xb, WqT, WkT, WvT, WoT, W1T, W2T);
    fused_rpe_qkv<<<1792, 256, 0, stream>>>(rpe, rpe_w, rpe_b, rpeW,
                                            xb, WqT, WkT, WvT, bq, bk, bv, qb, kbuf, vT);
    fused_rpe_attn<<<2048, 512, 0, stream>>>(rpe, rpe_w, rpe_b, rpeW,
                                             qb, kbuf, vT, opart, mlprt);
    fused_rpe_cw<<<1024, 256, 0, stream>>>(rpe, rpe_w, rpe_b, rpeW,
                                           opart, mlprt, WoT, PTb);
    gemm_big2<<<dim3(64, NC_GEMM), 512, 0, stream>>>(rpeW, PTb, gpart);
    megatail<<<256, 256, 0, stream>>>(gpart, bo, x, g1, lb1, W1T, b1, W2T, b2,
                                      g2, lb2, (float*)d_out);
}

// Round 16
// 133.596 us; speedup vs baseline: 10.0819x; 1.0376x over previous
//
#include <hip/hip_runtime.h>

typedef __attribute__((ext_vector_type(8))) short bf16x8;
typedef __attribute__((ext_vector_type(4))) float f32x4;

#define N_TOK 4096
#define NC_ATT 8
#define NC_GEMM 8

// rpe quad-range split across the three fused kernels (QUADS = 4096*4096/4)
#define RPE_QUADS 4194304L
#define RPE_Q1 629145L   // 15% -> K1
#define RPE_Q2 3355443L  // 80% -> K2 gets 65%, K3 gets 20%

static __device__ __forceinline__ ushort f2bf(float f) {
    union { float f; unsigned u; } x; x.f = f;
    unsigned u = x.u;
    unsigned r = (u + 0x7FFFu + ((u >> 16) & 1u)) >> 16;
    return (ushort)r;
}
// HW packed f32x2 -> bf16x2 (RNE), lo = a, hi = b
static __device__ __forceinline__ unsigned pkbf(float a, float b) {
    unsigned r;
    asm("v_cvt_pk_bf16_f32 %0, %1, %2" : "=v"(r) : "v"(a), "v"(b));
    return r;
}
static __device__ __forceinline__ float bf2f(ushort u) {
    union { unsigned u; float f; } x; x.u = (unsigned)u << 16; return x.f;
}

// rpe streaming body: process quad range [lo, hi)
static __device__ __forceinline__ void rpe_stream_role(
    const float* __restrict__ rpe, const float* __restrict__ rpe_w,
    const float* __restrict__ rpe_b, ushort* __restrict__ rpeW,
    long lo, long hi, int rb, long stride) {
    float w0 = rpe_w[0], w1 = rpe_w[1], w2 = rpe_w[2], w3 = rpe_w[3], w4 = rpe_w[4];
    float bb = rpe_b[0];
    const float4* p = (const float4*)rpe;
    for (long i = lo + (long)rb * blockDim.x + threadIdx.x; i < hi; i += stride) {
        float4 a0 = p[i];
        float4 a1 = p[i + RPE_QUADS];
        float4 a2 = p[i + 2 * RPE_QUADS];
        float4 a3 = p[i + 3 * RPE_QUADS];
        float4 a4 = p[i + 4 * RPE_QUADS];
        ushort4 o;
        unsigned lov = pkbf(bb + w0 * a0.x + w1 * a1.x + w2 * a2.x + w3 * a3.x + w4 * a4.x,
                            bb + w0 * a0.y + w1 * a1.y + w2 * a2.y + w3 * a3.y + w4 * a4.y);
        unsigned hiv = pkbf(bb + w0 * a0.z + w1 * a1.z + w2 * a2.z + w3 * a3.z + w4 * a4.z,
                            bb + w0 * a0.w + w1 * a1.w + w2 * a2.w + w3 * a3.w + w4 * a4.w);
        o.x = (ushort)lov; o.y = (ushort)(lov >> 16);
        o.z = (ushort)hiv; o.w = (ushort)(hiv >> 16);
        ((ushort4*)rpeW)[i] = o;
    }
}

// ---------------- prep: cast x + all weight transposes in one kernel ------
__global__ void prep_all(const float* __restrict__ x,
                         const float* __restrict__ Wq, const float* __restrict__ Wk,
                         const float* __restrict__ Wv, const float* __restrict__ Wo,
                         const float* __restrict__ W1, const float* __restrict__ W2,
                         ushort* __restrict__ xb, ushort* __restrict__ WqT,
                         ushort* __restrict__ WkT, ushort* __restrict__ WvT,
                         ushort* __restrict__ WoT, ushort* __restrict__ W1T,
                         ushort* __restrict__ W2T) {
    int i = blockIdx.x * 256 + threadIdx.x;
    if (i < 131072) {  // x: 4096*128/4 quads
        float4 v = ((const float4*)x)[i];
        ushort4 o;
        o.x = f2bf(v.x); o.y = f2bf(v.y); o.z = f2bf(v.z); o.w = f2bf(v.w);
        ((ushort4*)xb)[i] = o;
        return;
    }
    int j = i - 131072;
    int t = j >> 15, e = j & 32767;
    if (t < 3) {  // Wq/Wk/Wv [4][128][64] -> [4][64][128]
        const float* src = (t == 0 ? Wq : t == 1 ? Wk : Wv);
        ushort* dst = (t == 0 ? WqT : t == 1 ? WkT : WvT);
        int h = e >> 13, rem = e & 8191, d = rem >> 6, k = rem & 63;
        dst[h * 8192 + k * 128 + d] = f2bf(src[e]);
    } else if (t == 3) {  // Wo [256][128] -> [128][256]
        int r = e >> 7, c = e & 127;
        WoT[c * 256 + r] = f2bf(Wo[e]);
    } else if (t == 4) {  // W1 [128][256] -> [256][128]
        int r = e >> 8, c = e & 255;
        W1T[c * 128 + r] = f2bf(W1[e]);
    } else {  // W2 [256][128] -> [128][256]
        int r = e >> 7, c = e & 127;
        W2T[c * 256 + r] = f2bf(W2[e]);
    }
}

// ---------------- K1: qkv (blocks 0..767) || rpe stream [0,15%) ------------
__global__ __launch_bounds__(256) void fused_rpe_qkv(
    const float* __restrict__ rpe, const float* __restrict__ rpe_w,
    const float* __restrict__ rpe_b, ushort* __restrict__ rpeW,
    const ushort* __restrict__ xb, const ushort* __restrict__ WqT,
    const ushort* __restrict__ WkT, const ushort* __restrict__ WvT,
    const float* __restrict__ bq, const float* __restrict__ bk, const float* __restrict__ bv,
    ushort* __restrict__ qb, ushort* __restrict__ kb, ushort* __restrict__ vT) {
    int bid = blockIdx.x;
    if (bid >= 768) {
        rpe_stream_role(rpe, rpe_w, rpe_b, rpeW, 0L, RPE_Q1, bid - 768, (long)1024 * 256);
        return;
    }
    int m0 = (bid & 63) * 64;
    int y = bid >> 6;
    int h = y & 3, which = y >> 2;
    int wave = threadIdx.x >> 6, lane = threadIdx.x & 63;
    int fr = lane & 15, kg = lane >> 4;
    int wm = m0 + wave * 16;
    const ushort* WT = (which == 0 ? WqT : which == 1 ? WkT : WvT) + (long)h * 64 * 128;
    const float* bias = (which == 0 ? bq : which == 1 ? bk : bv) + h * 64;
    f32x4 acc[4] = {};
    for (int k0 = 0; k0 < 128; k0 += 32) {
        bf16x8 a = *(const bf16x8*)(xb + (long)(wm + fr) * 128 + k0 + kg * 8);
#pragma unroll
        for (int t = 0; t < 4; ++t) {
            bf16x8 b = *(const bf16x8*)(WT + (long)(t * 16 + fr) * 128 + k0 + kg * 8);
            acc[t] = __builtin_amdgcn_mfma_f32_16x16x32_bf16(a, b, acc[t], 0, 0, 0);
        }
    }
    int rb = wm + kg * 4;
#pragma unroll
    for (int t = 0; t < 4; ++t) {
        int col = t * 16 + fr;
        float bs = bias[col];
        if (which == 2) {
            ushort4 o;
            o.x = f2bf(fmaxf(acc[t][0] + bs, 0.f));
            o.y = f2bf(fmaxf(acc[t][1] + bs, 0.f));
            o.z = f2bf(fmaxf(acc[t][2] + bs, 0.f));
            o.w = f2bf(fmaxf(acc[t][3] + bs, 0.f));
            *(ushort4*)(vT + ((long)h * 64 + col) * N_TOK + rb) = o;
        } else {
            ushort* dst = (which == 0 ? qb : kb) + (long)h * N_TOK * 64;
            float scl = (which == 0) ? 0.125f * 1.44269504f : 1.0f;
#pragma unroll
            for (int r = 0; r < 4; ++r)
                dst[(long)(rb + r) * 64 + col] = f2bf(fmaxf(acc[t][r] + bs, 0.f) * scl);
        }
    }
}

// ---------------- K2: rpe stream [15%,80%) (even) || flash attn (odd) -------
// Attn: 1024 thr = 16 waves x 16 q-rows (TQ=256) sharing one K/V staging --
// halves cross-block K/V tile traffic vs TQ=128. Waves 0-7 stage K, 8-15 V.
__global__ __launch_bounds__(1024) void fused_rpe_attn(
    const float* __restrict__ rpe, const float* __restrict__ rpe_w,
    const float* __restrict__ rpe_b, ushort* __restrict__ rpeW,
    const ushort* __restrict__ qb, const ushort* __restrict__ kb,
    const ushort* __restrict__ vT, ushort* __restrict__ opart,
    float* __restrict__ mlpart) {
    __shared__ ushort Kt[2][64 * 64];
    __shared__ ushort Vt[2][64 * 64];
    __shared__ ushort Pl[16][16 * 64];
    int bid = blockIdx.x;
    int idx = bid >> 1;
    if ((bid & 1) == 0) {
        rpe_stream_role(rpe, rpe_w, rpe_b, rpeW, RPE_Q1, RPE_Q2, idx, (long)512 * 1024);
        return;
    }
    // ---------------- attention role ----------------
    int qt = idx & 15, h = (idx >> 4) & 3, cz = idx >> 6;
    int w = threadIdx.x >> 6, lane = threadIdx.x & 63;
    int fr = lane & 15, kg = lane >> 4;
    int lr = lane >> 3, lc = lane & 7;
    int swz = (lc ^ (lr & 7)) * 8;
    const ushort* qh = qb + (long)h * N_TOK * 64;
    const ushort* kh = kb + (long)h * N_TOK * 64;
    const ushort* vh = vT + (long)h * 64 * N_TOK;
    int q0 = qt * 256 + w * 16;
    bf16x8 qf0 = *(const bf16x8*)(qh + (long)(q0 + fr) * 64 + kg * 8);
    bf16x8 qf1 = *(const bf16x8*)(qh + (long)(q0 + fr) * 64 + 32 + kg * 8);
    f32x4 o[4] = {};
    float lsum = 0.f;
    int nbase = cz * (N_TOK / NC_ATT);
    auto stage = [&](int buf, int s) {
        int n0 = nbase + s * 64;
        if (w < 8) {
            int row = w * 8 + lr;
            __builtin_amdgcn_global_load_lds(
                (const __attribute__((address_space(1))) unsigned int*)(kh + (long)(n0 + row) * 64 + swz),
                (__attribute__((address_space(3))) unsigned int*)(&Kt[buf][w * 512]), 16, 0, 0);
        } else {
            int row = (w - 8) * 8 + lr;
            __builtin_amdgcn_global_load_lds(
                (const __attribute__((address_space(1))) unsigned int*)(vh + (long)row * N_TOK + n0 + swz),
                (__attribute__((address_space(3))) unsigned int*)(&Vt[buf][(w - 8) * 512]), 16, 0, 0);
        }
    };
    stage(0, 0);
    __syncthreads();
    const int NS = (N_TOK / NC_ATT) / 64;
    for (int s = 0; s < NS; ++s) {
        int buf = s & 1;
        if (s + 1 < NS) stage(buf ^ 1, s + 1);
        // S^T = K @ Q^T: lane holds kv = t*16+kg*4+r for q = q0+fr
        f32x4 sc[4] = {};
        __builtin_amdgcn_s_setprio(1);
#pragma unroll
        for (int t = 0; t < 4; ++t) {
            int row = t * 16 + fr;
            bf16x8 k0 = *(const bf16x8*)(&Kt[buf][row * 64 + ((kg * 8) ^ ((row & 7) * 8))]);
            bf16x8 k1 = *(const bf16x8*)(&Kt[buf][row * 64 + ((32 + kg * 8) ^ ((row & 7) * 8))]);
            sc[t] = __builtin_amdgcn_mfma_f32_16x16x32_bf16(k0, qf0, sc[t], 0, 0, 0);
            sc[t] = __builtin_amdgcn_mfma_f32_16x16x32_bf16(k1, qf1, sc[t], 0, 0, 0);
        }
        __builtin_amdgcn_s_setprio(0);
#pragma unroll
        for (int t = 0; t < 4; ++t)
#pragma unroll
            for (int r = 0; r < 4; ++r) {
                float p = exp2f(sc[t][r]);
                sc[t][r] = p;
                lsum += p;
            }
#pragma unroll
        for (int t = 0; t < 4; ++t) {
            uint2 u;
            u.x = pkbf(sc[t][0], sc[t][1]);
            u.y = pkbf(sc[t][2], sc[t][3]);
            *(uint2*)(&Pl[w][fr * 64 + ((t * 16 + kg * 4) ^ ((fr & 7) * 8))]) = u;
        }
        __builtin_amdgcn_s_setprio(1);
#pragma unroll
        for (int ks = 0; ks < 2; ++ks) {
            bf16x8 pf = *(const bf16x8*)(&Pl[w][fr * 64 + ((ks * 32 + kg * 8) ^ ((fr & 7) * 8))]);
#pragma unroll
            for (int t = 0; t < 4; ++t) {
                int row = t * 16 + fr;
                bf16x8 b = *(const bf16x8*)(&Vt[buf][row * 64 + ((ks * 32 + kg * 8) ^ ((row & 7) * 8))]);
                o[t] = __builtin_amdgcn_mfma_f32_16x16x32_bf16(pf, b, o[t], 0, 0, 0);
            }
        }
        __builtin_amdgcn_s_setprio(0);
        __syncthreads();
    }
    // row sum for q=fr lives across lanes {fr, fr+16, fr+32, fr+48}
    lsum += __shfl_xor(lsum, 16);
    lsum += __shfl_xor(lsum, 32);
    float linv = 1.0f / lsum;
    float lq[4];
#pragma unroll
    for (int r = 0; r < 4; ++r) lq[r] = __shfl(linv, kg * 4 + r);
    ushort* ob = opart + (((long)cz * 4 + h) * N_TOK + q0 + kg * 4) * 64;
#pragma unroll
    for (int t = 0; t < 4; ++t)
#pragma unroll
        for (int r = 0; r < 4; ++r)
            ob[(long)r * 64 + t * 16 + fr] = f2bf(o[t][r] * lq[r]);
    if (lane < 16)
        mlpart[((long)cz * 4 + h) * N_TOK + q0 + lane] = lsum;
}

// ---------------- K3: combine+Wo (blocks 0..255) || rpe stream [80%,100%) ---
__global__ __launch_bounds__(256) void fused_rpe_cw(
    const float* __restrict__ rpe, const float* __restrict__ rpe_w,
    const float* __restrict__ rpe_b, ushort* __restrict__ rpeW,
    const ushort* __restrict__ opart, const float* __restrict__ mlpart,
    const ushort* __restrict__ WoT, ushort* __restrict__ PT) {
    int bid = blockIdx.x;
    if (bid >= 256) {
        rpe_stream_role(rpe, rpe_w, rpe_b, rpeW, RPE_Q2, RPE_QUADS, bid - 256, (long)768 * 256);
        return;
    }
    int q0 = bid * 16;
    int tid = threadIdx.x;
    __shared__ ushort mt[16 * 256];
    {
        int q = tid >> 4, cg = tid & 15;  // 16 rows x 16 col-groups (16 cols each)
        int h = cg >> 2;                  // head for this 16-col group
        long qg = q0 + q;
        float L = 0.f, co[NC_ATT];
#pragma unroll
        for (int c = 0; c < NC_ATT; ++c) {
            co[c] = mlpart[((long)c * 4 + h) * N_TOK + qg];
            L += co[c];
        }
        float inv = 1.0f / L;
#pragma unroll
        for (int c = 0; c < NC_ATT; ++c) co[c] *= inv;
        float a[16];
#pragma unroll
        for (int j = 0; j < 16; ++j) a[j] = 0.f;
#pragma unroll
        for (int c = 0; c < NC_ATT; ++c) {
            const ushort* pr = opart + (((long)c * 4 + h) * N_TOK + qg) * 64 + (cg & 3) * 16;
            bf16x8 v0 = *(const bf16x8*)(pr);
            bf16x8 v1 = *(const bf16x8*)(pr + 8);
#pragma unroll
            for (int j = 0; j < 8; ++j) {
                a[j] += co[c] * bf2f((ushort)v0[j]);
                a[8 + j] += co[c] * bf2f((ushort)v1[j]);
            }
        }
        int c0 = cg * 16;
#pragma unroll
        for (int g = 0; g < 4; ++g) {
            uint2 u;
            u.x = pkbf(a[g * 4 + 0], a[g * 4 + 1]);
            u.y = pkbf(a[g * 4 + 2], a[g * 4 + 3]);
            *(uint2*)(&mt[q * 256 + ((c0 + g * 4) ^ ((q & 7) * 8))]) = u;
        }
    }
    __syncthreads();
    {
        int w = tid >> 6, lane = tid & 63;
        int fr = lane & 15, kg = lane >> 4;
        f32x4 acc[2] = {};
        for (int k0 = 0; k0 < 256; k0 += 32) {
            bf16x8 a0 = *(const bf16x8*)(WoT + (long)(w * 32 + fr) * 256 + k0 + kg * 8);
            bf16x8 a1 = *(const bf16x8*)(WoT + (long)(w * 32 + 16 + fr) * 256 + k0 + kg * 8);
            bf16x8 b = *(const bf16x8*)(&mt[fr * 256 + ((k0 + kg * 8) ^ ((fr & 7) * 8))]);
            acc[0] = __builtin_amdgcn_mfma_f32_16x16x32_bf16(a0, b, acc[0], 0, 0, 0);
            acc[1] = __builtin_amdgcn_mfma_f32_16x16x32_bf16(a1, b, acc[1], 0, 0, 0);
        }
#pragma unroll
        for (int dt = 0; dt < 2; ++dt)
#pragma unroll
            for (int r = 0; r < 4; ++r)
                PT[(long)(w * 32 + dt * 16 + kg * 4 + r) * N_TOK + q0 + fr] =
                    f2bf(acc[dt][r]);
    }
}

// ---------------- gemm2: part[c] = rpeW[.,Kc] @ PT^T (both bf16, gload_lds) -
__global__ __launch_bounds__(512) void gemm_big2(
    const ushort* __restrict__ A, const ushort* __restrict__ PT,
    float* __restrict__ part) {
    int mt = blockIdx.x, cz = blockIdx.y;
    int tid = threadIdx.x;
    int w = tid >> 6, lane = tid & 63;
    int fr = lane & 15, kg = lane >> 4;
    int lr = lane >> 3, lc = lane & 7;
    int swz = (lc ^ (lr & 7)) * 8;
    int ms = w >> 1, nh = w & 1;
    __shared__ ushort At[2][64 * 64];    // 16 KB
    __shared__ ushort Bt[2][128 * 64];   // 32 KB
    int m0 = mt * 64;
    long kbase = (long)cz * (N_TOK / NC_GEMM);
    int arow = ms * 16 + fr;
    auto stage = [&](int buf, int s) {
        long kc = kbase + s * 64 + swz;
        int rowA = w * 8 + lr;
        __builtin_amdgcn_global_load_lds(
            (const __attribute__((address_space(1))) unsigned int*)(A + (long)(m0 + rowA) * N_TOK + kc),
            (__attribute__((address_space(3))) unsigned int*)(&At[buf][w * 512]), 16, 0, 0);
#pragma unroll
        for (int j = 0; j < 2; ++j) {
            int row = w * 16 + j * 8 + lr;
            __builtin_amdgcn_global_load_lds(
                (const __attribute__((address_space(1))) unsigned int*)(PT + (long)row * N_TOK + kc),
                (__attribute__((address_space(3))) unsigned int*)(&Bt[buf][(w * 2 + j) * 512]), 16, 0, 0);
        }
    };
    f32x4 acc[4] = {};
    stage(0, 0);
    __syncthreads();
    const int NS = (N_TOK / NC_GEMM) / 64;
    for (int s = 0; s < NS; ++s) {
        int buf = s & 1;
        if (s + 1 < NS) stage(buf ^ 1, s + 1);
        __builtin_amdgcn_s_setprio(1);
#pragma unroll
        for (int ks = 0; ks < 2; ++ks) {
            int c = ks * 32 + kg * 8;
            bf16x8 av = *(const bf16x8*)(&At[buf][arow * 64 + (c ^ ((arow & 7) * 8))]);
#pragma unroll
            for (int nf = 0; nf < 4; ++nf) {
                int row = nh * 64 + nf * 16 + fr;
                bf16x8 b = *(const bf16x8*)(&Bt[buf][row * 64 + (c ^ ((row & 7) * 8))]);
                acc[nf] = __builtin_amdgcn_mfma_f32_16x16x32_bf16(av, b, acc[nf], 0, 0, 0);
            }
        }
        __builtin_amdgcn_s_setprio(0);
        __syncthreads();
    }
    float* pb = part + ((long)cz * N_TOK + m0 + ms * 16 + kg * 4) * 128 + nh * 64 + fr;
#pragma unroll
    for (int nf = 0; nf < 4; ++nf)
#pragma unroll
        for (int r = 0; r < 4; ++r)
            pb[(long)r * 128 + nf * 16] = acc[nf][r];
}

// ---------------- megatail: sum parts + bo + x -> LN1 -> FFN -> LN2 -> out --
__global__ __launch_bounds__(256) void megatail(
    const float* __restrict__ gpart, const float* __restrict__ bo,
    const float* __restrict__ x, const float* __restrict__ g1,
    const float* __restrict__ lb1, const ushort* __restrict__ W1T,
    const float* __restrict__ b1, const ushort* __restrict__ W2T,
    const float* __restrict__ b2, const float* __restrict__ g2,
    const float* __restrict__ lb2, float* __restrict__ out) {
    int r0 = blockIdx.x * 16;
    int tid = threadIdx.x;
    int w = tid >> 6, lane = tid & 63;
    int fr = lane & 15, kg = lane >> 4;
    __shared__ float x1f[16][132];
    __shared__ ushort x1b[16][128];
    __shared__ ushort hbuf[16][256];
    __shared__ float otile[16][132];
    int row = tid >> 4, c0 = (tid & 15) * 8;
    {
        float v[8];
        float4 s0 = {0.f, 0.f, 0.f, 0.f}, s1 = {0.f, 0.f, 0.f, 0.f};
#pragma unroll
        for (int c = 0; c < NC_GEMM; ++c) {
            const float* pr = gpart + ((long)c * N_TOK + r0 + row) * 128 + c0;
            float4 a = *(const float4*)(pr);
            float4 b = *(const float4*)(pr + 4);
            s0.x += a.x; s0.y += a.y; s0.z += a.z; s0.w += a.w;
            s1.x += b.x; s1.y += b.y; s1.z += b.z; s1.w += b.w;
        }
        const float* xr = x + (long)(r0 + row) * 128 + c0;
        v[0] = s0.x + bo[c0 + 0] + xr[0];
        v[1] = s0.y + bo[c0 + 1] + xr[1];
        v[2] = s0.z + bo[c0 + 2] + xr[2];
        v[3] = s0.w + bo[c0 + 3] + xr[3];
        v[4] = s1.x + bo[c0 + 4] + xr[4];
        v[5] = s1.y + bo[c0 + 5] + xr[5];
        v[6] = s1.z + bo[c0 + 6] + xr[6];
        v[7] = s1.w + bo[c0 + 7] + xr[7];
        float s = 0.f;
#pragma unroll
        for (int jj = 0; jj < 8; ++jj) s += v[jj];
#pragma unroll
        for (int off = 1; off < 16; off <<= 1) s += __shfl_xor(s, off);
        float mean = s * (1.0f / 128.0f);
        float ss = 0.f;
#pragma unroll
        for (int jj = 0; jj < 8; ++jj) { float d = v[jj] - mean; ss += d * d; }
#pragma unroll
        for (int off = 1; off < 16; off <<= 1) ss += __shfl_xor(ss, off);
        float rstd = rsqrtf(ss * (1.0f / 128.0f) + 1e-5f);
        union { bf16x8 vec; ushort us[8]; } pk8;
#pragma unroll
        for (int jj = 0; jj < 8; ++jj) {
            float y = (v[jj] - mean) * rstd * g1[c0 + jj] + lb1[c0 + jj];
            x1f[row][c0 + jj] = y;
            pk8.us[jj] = f2bf(y);
        }
        *(bf16x8*)(&x1b[row][c0 ^ ((row & 7) * 8)]) = pk8.vec;
    }
    __syncthreads();
    {
        f32x4 a1[4] = {};
#pragma unroll
        for (int ks = 0; ks < 4; ++ks) {
            bf16x8 a = *(const bf16x8*)(&x1b[fr][(ks * 32 + kg * 8) ^ ((fr & 7) * 8)]);
#pragma unroll
            for (int t = 0; t < 4; ++t) {
                bf16x8 b = *(const bf16x8*)(W1T + (long)(w * 64 + t * 16 + fr) * 128 + ks * 32 + kg * 8);
                a1[t] = __builtin_amdgcn_mfma_f32_16x16x32_bf16(a, b, a1[t], 0, 0, 0);
            }
        }
#pragma unroll
        for (int t = 0; t < 4; ++t) {
            int col = w * 64 + t * 16 + fr;
            float bs = b1[col];
#pragma unroll
            for (int r = 0; r < 4; ++r) {
                int rr = kg * 4 + r;
                hbuf[rr][col ^ ((rr & 7) * 8)] = f2bf(fmaxf(a1[t][r] + bs, 0.f));
            }
        }
    }
    __syncthreads();
    {
        f32x4 a2[2] = {};
#pragma unroll
        for (int ks = 0; ks < 8; ++ks) {
            bf16x8 a = *(const bf16x8*)(&hbuf[fr][(ks * 32 + kg * 8) ^ ((fr & 7) * 8)]);
#pragma unroll
            for (int t = 0; t < 2; ++t) {
                bf16x8 b = *(const bf16x8*)(W2T + (long)(w * 32 + t * 16 + fr) * 256 + ks * 32 + kg * 8);
                a2[t] = __builtin_amdgcn_mfma_f32_16x16x32_bf16(a, b, a2[t], 0, 0, 0);
            }
        }
#pragma unroll
        for (int t = 0; t < 2; ++t) {
            int col = w * 32 + t * 16 + fr;
            float bs = b2[col];
#pragma unroll
            for (int r = 0; r < 4; ++r) {
                int rr = kg * 4 + r;
                otile[rr][col] = a2[t][r] + bs + x1f[rr][col];
            }
        }
    }
    __syncthreads();
    {
        float v[8];
        float s = 0.f;
#pragma unroll
        for (int jj = 0; jj < 8; ++jj) { v[jj] = otile[row][c0 + jj]; s += v[jj]; }
#pragma unroll
        for (int off = 1; off < 16; off <<= 1) s += __shfl_xor(s, off);
        float mean = s * (1.0f / 128.0f);
        float ss = 0.f;
#pragma unroll
        for (int jj = 0; jj < 8; ++jj) { float d = v[jj] - mean; ss += d * d; }
#pragma unroll
        for (int off = 1; off < 16; off <<= 1) ss += __shfl_xor(ss, off);
        float rstd = rsqrtf(ss * (1.0f / 128.0f) + 1e-5f);
#pragma unroll
        for (int jj = 0; jj < 8; ++jj) {
            float y = (v[jj] - mean) * rstd * g2[c0 + jj] + lb2[c0 + jj];
            out[(long)(r0 + row) * 128 + c0 + jj] = y;
        }
    }
}

extern "C" void kernel_launch(void* const* d_in, const int* in_sizes, int n_in,
                              void* d_out, int out_size, void* d_ws, size_t ws_size,
                              hipStream_t stream) {
    const float* x     = (const float*)d_in[0];
    const float* rpe   = (const float*)d_in[1];
    const float* Wq    = (const float*)d_in[2];
    const float* bq    = (const float*)d_in[3];
    const float* Wk    = (const float*)d_in[4];
    const float* bk    = (const float*)d_in[5];
    const float* Wv    = (const float*)d_in[6];
    const float* bv    = (const float*)d_in[7];
    const float* rpe_w = (const float*)d_in[8];
    const float* rpe_b = (const float*)d_in[9];
    const float* Wo    = (const float*)d_in[10];
    const float* bo    = (const float*)d_in[11];
    const float* W1    = (const float*)d_in[12];
    const float* b1    = (const float*)d_in[13];
    const float* W2    = (const float*)d_in[14];
    const float* b2    = (const float*)d_in[15];
    const float* g1    = (const float*)d_in[16];
    const float* lb1   = (const float*)d_in[17];
    const float* g2    = (const float*)d_in[18];
    const float* lb2   = (const float*)d_in[19];

    char* wp = (char*)d_ws;
    auto alloc = [&](size_t sz) { char* p = wp; wp += (sz + 255) & ~(size_t)255; return p; };
    ushort* xb    = (ushort*)alloc((size_t)4096 * 128 * 2);
    ushort* WqT   = (ushort*)alloc((size_t)4 * 64 * 128 * 2);
    ushort* WkT   = (ushort*)alloc((size_t)4 * 64 * 128 * 2);
    ushort* WvT   = (ushort*)alloc((size_t)4 * 64 * 128 * 2);
    ushort* WoT   = (ushort*)alloc((size_t)128 * 256 * 2);
    ushort* W1T   = (ushort*)alloc((size_t)256 * 128 * 2);
    ushort* W2T   = (ushort*)alloc((size_t)128 * 256 * 2);
    ushort* qb    = (ushort*)alloc((size_t)4 * 4096 * 64 * 2);
    ushort* kbuf  = (ushort*)alloc((size_t)4 * 4096 * 64 * 2);
    ushort* vT    = (ushort*)alloc((size_t)4 * 64 * 4096 * 2);
    ushort* rpeW  = (ushort*)alloc((size_t)4096 * 4096 * 2);
    ushort* PTb   = (ushort*)alloc((size_t)128 * 4096 * 2);
    ushort* opart = (ushort*)alloc((size_t)NC_ATT * 4 * 4096 * 64 * 2);
    float*  mlprt = (float*)alloc((size_t)NC_ATT * 4 * 4096 * 4);
    float*  gpart = (float*)alloc((size_t)NC_GEMM * 4096 * 128 * 4);

    prep_all<<<1280, 256, 0, stream>>>(x, Wq, Wk, Wv, Wo, W1, W2,
                                       xb, WqT, WkT, WvT, WoT, W1T, W2T);
    fused_rpe_qkv<<<1792, 256, 0, stream>>>(rpe, rpe_w, rpe_b, rpeW,
                                            xb, WqT, WkT, WvT, bq, bk, bv, qb, kbuf, vT);
    fused_rpe_attn<<<1024, 1024, 0, stream>>>(rpe, rpe_w, rpe_b, rpeW,
                                              qb, kbuf, vT, opart, mlprt);
    fused_rpe_cw<<<1024, 256, 0, stream>>>(rpe, rpe_w, rpe_b, rpeW,
                                           opart, mlprt, WoT, PTb);
    gemm_big2<<<dim3(64, NC_GEMM), 512, 0, stream>>>(rpeW, PTb, gpart);
    megatail<<<256, 256, 0, stream>>>(gpart, bo, x, g1, lb1, W1T, b1, W2T, b2,
                                      g2, lb2, (float*)d_out);
}

// Round 17
// 131.215 us; speedup vs baseline: 10.2649x; 1.0182x over previous
//
#include <hip/hip_runtime.h>

typedef __attribute__((ext_vector_type(8))) short bf16x8;
typedef __attribute__((ext_vector_type(4))) float f32x4;

#define N_TOK 4096
#define NC_ATT 8
#define NC_GEMM 8

// rpe quad-range split across the three fused kernels (QUADS = 4096*4096/4)
#define RPE_QUADS 4194304L
#define RPE_Q1 629145L   // 15%
#define RPE_Q2 3355443L  // 80%

static __device__ __forceinline__ ushort f2bf(float f) {
    union { float f; unsigned u; } x; x.f = f;
    unsigned u = x.u;
    unsigned r = (u + 0x7FFFu + ((u >> 16) & 1u)) >> 16;
    return (ushort)r;
}
// HW packed f32x2 -> bf16x2 (RNE), lo = a, hi = b
static __device__ __forceinline__ unsigned pkbf(float a, float b) {
    unsigned r;
    asm("v_cvt_pk_bf16_f32 %0, %1, %2" : "=v"(r) : "v"(a), "v"(b));
    return r;
}
static __device__ __forceinline__ float bf2f(ushort u) {
    union { unsigned u; float f; } x; x.u = (unsigned)u << 16; return x.f;
}

// rpe streaming body: process quad range [lo, hi) with nb blocks of T threads
static __device__ __forceinline__ void rpe_stream_role(
    const float* __restrict__ rpe, const float* __restrict__ rpe_w,
    const float* __restrict__ rpe_b, ushort* __restrict__ rpeW,
    long lo, long hi, int rb, long stride) {
    float w0 = rpe_w[0], w1 = rpe_w[1], w2 = rpe_w[2], w3 = rpe_w[3], w4 = rpe_w[4];
    float bb = rpe_b[0];
    const float4* p = (const float4*)rpe;
    for (long i = lo + (long)rb * blockDim.x + threadIdx.x; i < hi; i += stride) {
        float4 a0 = p[i];
        float4 a1 = p[i + RPE_QUADS];
        float4 a2 = p[i + 2 * RPE_QUADS];
        float4 a3 = p[i + 3 * RPE_QUADS];
        float4 a4 = p[i + 4 * RPE_QUADS];
        ushort4 o;
        unsigned lov = pkbf(bb + w0 * a0.x + w1 * a1.x + w2 * a2.x + w3 * a3.x + w4 * a4.x,
                            bb + w0 * a0.y + w1 * a1.y + w2 * a2.y + w3 * a3.y + w4 * a4.y);
        unsigned hiv = pkbf(bb + w0 * a0.z + w1 * a1.z + w2 * a2.z + w3 * a3.z + w4 * a4.z,
                            bb + w0 * a0.w + w1 * a1.w + w2 * a2.w + w3 * a3.w + w4 * a4.w);
        o.x = (ushort)lov; o.y = (ushort)(lov >> 16);
        o.z = (ushort)hiv; o.w = (ushort)(hiv >> 16);
        ((ushort4*)rpeW)[i] = o;
    }
}

// ---------------- prep: cast x + all weight transposes in one kernel ------
__global__ void prep_all(const float* __restrict__ x,
                         const float* __restrict__ Wq, const float* __restrict__ Wk,
                         const float* __restrict__ Wv, const float* __restrict__ Wo,
                         const float* __restrict__ W1, const float* __restrict__ W2,
                         ushort* __restrict__ xb, ushort* __restrict__ WqT,
                         ushort* __restrict__ WkT, ushort* __restrict__ WvT,
                         ushort* __restrict__ WoT, ushort* __restrict__ W1T,
                         ushort* __restrict__ W2T) {
    int i = blockIdx.x * 256 + threadIdx.x;
    if (i < 131072) {  // x: 4096*128/4 quads
        float4 v = ((const float4*)x)[i];
        ushort4 o;
        o.x = f2bf(v.x); o.y = f2bf(v.y); o.z = f2bf(v.z); o.w = f2bf(v.w);
        ((ushort4*)xb)[i] = o;
        return;
    }
    int j = i - 131072;
    int t = j >> 15, e = j & 32767;
    if (t < 3) {  // Wq/Wk/Wv [4][128][64] -> [4][64][128]
        const float* src = (t == 0 ? Wq : t == 1 ? Wk : Wv);
        ushort* dst = (t == 0 ? WqT : t == 1 ? WkT : WvT);
        int h = e >> 13, rem = e & 8191, d = rem >> 6, k = rem & 63;
        dst[h * 8192 + k * 128 + d] = f2bf(src[e]);
    } else if (t == 3) {  // Wo [256][128] -> [128][256]
        int r = e >> 7, c = e & 127;
        WoT[c * 256 + r] = f2bf(Wo[e]);
    } else if (t == 4) {  // W1 [128][256] -> [256][128]
        int r = e >> 8, c = e & 255;
        W1T[c * 128 + r] = f2bf(W1[e]);
    } else {  // W2 [256][128] -> [128][256]
        int r = e >> 7, c = e & 127;
        W2T[c * 256 + r] = f2bf(W2[e]);
    }
}

// ---------------- K1: qkv (blocks 0..767) || rpe stream [0,15%) ------------
__global__ __launch_bounds__(256) void fused_rpe_qkv(
    const float* __restrict__ rpe, const float* __restrict__ rpe_w,
    const float* __restrict__ rpe_b, ushort* __restrict__ rpeW,
    const ushort* __restrict__ xb, const ushort* __restrict__ WqT,
    const ushort* __restrict__ WkT, const ushort* __restrict__ WvT,
    const float* __restrict__ bq, const float* __restrict__ bk, const float* __restrict__ bv,
    ushort* __restrict__ qb, ushort* __restrict__ kb, ushort* __restrict__ vT) {
    int bid = blockIdx.x;
    if (bid >= 768) {
        rpe_stream_role(rpe, rpe_w, rpe_b, rpeW, 0L, RPE_Q1, bid - 768, (long)1024 * 256);
        return;
    }
    int m0 = (bid & 63) * 64;
    int y = bid >> 6;
    int h = y & 3, which = y >> 2;
    int wave = threadIdx.x >> 6, lane = threadIdx.x & 63;
    int fr = lane & 15, kg = lane >> 4;
    int wm = m0 + wave * 16;
    const ushort* WT = (which == 0 ? WqT : which == 1 ? WkT : WvT) + (long)h * 64 * 128;
    const float* bias = (which == 0 ? bq : which == 1 ? bk : bv) + h * 64;
    f32x4 acc[4] = {};
    for (int k0 = 0; k0 < 128; k0 += 32) {
        bf16x8 a = *(const bf16x8*)(xb + (long)(wm + fr) * 128 + k0 + kg * 8);
#pragma unroll
        for (int t = 0; t < 4; ++t) {
            bf16x8 b = *(const bf16x8*)(WT + (long)(t * 16 + fr) * 128 + k0 + kg * 8);
            acc[t] = __builtin_amdgcn_mfma_f32_16x16x32_bf16(a, b, acc[t], 0, 0, 0);
        }
    }
    int rb = wm + kg * 4;
#pragma unroll
    for (int t = 0; t < 4; ++t) {
        int col = t * 16 + fr;
        float bs = bias[col];
        if (which == 2) {
            ushort4 o;
            o.x = f2bf(fmaxf(acc[t][0] + bs, 0.f));
            o.y = f2bf(fmaxf(acc[t][1] + bs, 0.f));
            o.z = f2bf(fmaxf(acc[t][2] + bs, 0.f));
            o.w = f2bf(fmaxf(acc[t][3] + bs, 0.f));
            *(ushort4*)(vT + ((long)h * 64 + col) * N_TOK + rb) = o;
        } else {
            ushort* dst = (which == 0 ? qb : kb) + (long)h * N_TOK * 64;
            float scl = (which == 0) ? 0.125f * 1.44269504f : 1.0f;
#pragma unroll
            for (int r = 0; r < 4; ++r)
                dst[(long)(rb + r) * 64 + col] = f2bf(fmaxf(acc[t][r] + bs, 0.f) * scl);
        }
    }
}

// ---------------- K2: rpe stream [15%,80%) (even) || flash attn (odd) -------
__global__ __launch_bounds__(512, 6) void fused_rpe_attn(
    const float* __restrict__ rpe, const float* __restrict__ rpe_w,
    const float* __restrict__ rpe_b, ushort* __restrict__ rpeW,
    const ushort* __restrict__ qb, const ushort* __restrict__ kb,
    const ushort* __restrict__ vT, ushort* __restrict__ opart,
    float* __restrict__ mlpart) {
    __shared__ ushort Kt[2][64 * 64];
    __shared__ ushort Vt[2][64 * 64];
    __shared__ ushort Pl[8][16 * 64];
    int bid = blockIdx.x;
    int idx = bid >> 1;
    if ((bid & 1) == 0) {
        rpe_stream_role(rpe, rpe_w, rpe_b, rpeW, RPE_Q1, RPE_Q2, idx, (long)1024 * 512);
        return;
    }
    // ---------------- attention role ----------------
    int qt = idx & 31, h = (idx >> 5) & 3, cz = idx >> 7;
    int w = threadIdx.x >> 6, lane = threadIdx.x & 63;
    int fr = lane & 15, kg = lane >> 4;
    int lr = lane >> 3, lc = lane & 7;
    int swz = (lc ^ (lr & 7)) * 8;
    const ushort* qh = qb + (long)h * N_TOK * 64;
    const ushort* kh = kb + (long)h * N_TOK * 64;
    const ushort* vh = vT + (long)h * 64 * N_TOK;
    int q0 = qt * 128 + w * 16;
    bf16x8 qf0 = *(const bf16x8*)(qh + (long)(q0 + fr) * 64 + kg * 8);
    bf16x8 qf1 = *(const bf16x8*)(qh + (long)(q0 + fr) * 64 + 32 + kg * 8);
    f32x4 o[4] = {};
    float lsum = 0.f;
    int nbase = cz * (N_TOK / NC_ATT);
    auto stage = [&](int buf, int s) {
        int n0 = nbase + s * 64;
        int row = w * 8 + lr;  // wave w stages rows w*8..w*8+7 (1 instr each)
        __builtin_amdgcn_global_load_lds(
            (const __attribute__((address_space(1))) unsigned int*)(kh + (long)(n0 + row) * 64 + swz),
            (__attribute__((address_space(3))) unsigned int*)(&Kt[buf][w * 512]), 16, 0, 0);
        __builtin_amdgcn_global_load_lds(
            (const __attribute__((address_space(1))) unsigned int*)(vh + (long)row * N_TOK + n0 + swz),
            (__attribute__((address_space(3))) unsigned int*)(&Vt[buf][w * 512]), 16, 0, 0);
    };
    stage(0, 0);
    __syncthreads();
    const int NS = (N_TOK / NC_ATT) / 64;
    for (int s = 0; s < NS; ++s) {
        int buf = s & 1;
        if (s + 1 < NS) stage(buf ^ 1, s + 1);
        // S^T = K @ Q^T: lane holds kv = t*16+kg*4+r for q = q0+fr
        f32x4 sc[4] = {};
        __builtin_amdgcn_s_setprio(1);
#pragma unroll
        for (int t = 0; t < 4; ++t) {
            int row = t * 16 + fr;
            bf16x8 k0 = *(const bf16x8*)(&Kt[buf][row * 64 + ((kg * 8) ^ ((row & 7) * 8))]);
            bf16x8 k1 = *(const bf16x8*)(&Kt[buf][row * 64 + ((32 + kg * 8) ^ ((row & 7) * 8))]);
            sc[t] = __builtin_amdgcn_mfma_f32_16x16x32_bf16(k0, qf0, sc[t], 0, 0, 0);
            sc[t] = __builtin_amdgcn_mfma_f32_16x16x32_bf16(k1, qf1, sc[t], 0, 0, 0);
        }
        __builtin_amdgcn_s_setprio(0);
#pragma unroll
        for (int t = 0; t < 4; ++t)
#pragma unroll
            for (int r = 0; r < 4; ++r) {
                float p = exp2f(sc[t][r]);
                sc[t][r] = p;
                lsum += p;
            }
#pragma unroll
        for (int t = 0; t < 4; ++t) {
            uint2 u;
            u.x = pkbf(sc[t][0], sc[t][1]);
            u.y = pkbf(sc[t][2], sc[t][3]);
            *(uint2*)(&Pl[w][fr * 64 + ((t * 16 + kg * 4) ^ ((fr & 7) * 8))]) = u;
        }
        __builtin_amdgcn_s_setprio(1);
#pragma unroll
        for (int ks = 0; ks < 2; ++ks) {
            bf16x8 pf = *(const bf16x8*)(&Pl[w][fr * 64 + ((ks * 32 + kg * 8) ^ ((fr & 7) * 8))]);
#pragma unroll
            for (int t = 0; t < 4; ++t) {
                int row = t * 16 + fr;
                bf16x8 b = *(const bf16x8*)(&Vt[buf][row * 64 + ((ks * 32 + kg * 8) ^ ((row & 7) * 8))]);
                o[t] = __builtin_amdgcn_mfma_f32_16x16x32_bf16(pf, b, o[t], 0, 0, 0);
            }
        }
        __builtin_amdgcn_s_setprio(0);
        __syncthreads();
    }
    // row sum for q=fr lives across lanes {fr, fr+16, fr+32, fr+48}
    lsum += __shfl_xor(lsum, 16);
    lsum += __shfl_xor(lsum, 32);
    float linv = 1.0f / lsum;
    float lq[4];
#pragma unroll
    for (int r = 0; r < 4; ++r) lq[r] = __shfl(linv, kg * 4 + r);
    ushort* ob = opart + (((long)cz * 4 + h) * N_TOK + q0 + kg * 4) * 64;
#pragma unroll
    for (int t = 0; t < 4; ++t)
#pragma unroll
        for (int r = 0; r < 4; ++r)
            ob[(long)r * 64 + t * 16 + fr] = f2bf(o[t][r] * lq[r]);
    if (lane < 16)
        mlpart[((long)cz * 4 + h) * N_TOK + q0 + lane] = lsum;
}

// ---------------- K3: combine+Wo (blocks 0..255) || rpe stream [80%,100%) ---
__global__ __launch_bounds__(256) void fused_rpe_cw(
    const float* __restrict__ rpe, const float* __restrict__ rpe_w,
    const float* __restrict__ rpe_b, ushort* __restrict__ rpeW,
    const ushort* __restrict__ opart, const float* __restrict__ mlpart,
    const ushort* __restrict__ WoT, ushort* __restrict__ PT) {
    int bid = blockIdx.x;
    if (bid >= 256) {
        rpe_stream_role(rpe, rpe_w, rpe_b, rpeW, RPE_Q2, RPE_QUADS, bid - 256, (long)768 * 256);
        return;
    }
    int q0 = bid * 16;
    int tid = threadIdx.x;
    __shared__ ushort mt[16 * 256];
    {
        int q = tid >> 4, cg = tid & 15;  // 16 rows x 16 col-groups (16 cols each)
        int h = cg >> 2;                  // head for this 16-col group
        long qg = q0 + q;
        float L = 0.f, co[NC_ATT];
#pragma unroll
        for (int c = 0; c < NC_ATT; ++c) {
            co[c] = mlpart[((long)c * 4 + h) * N_TOK + qg];
            L += co[c];
        }
        float inv = 1.0f / L;
#pragma unroll
        for (int c = 0; c < NC_ATT; ++c) co[c] *= inv;
        float a[16];
#pragma unroll
        for (int j = 0; j < 16; ++j) a[j] = 0.f;
#pragma unroll
        for (int c = 0; c < NC_ATT; ++c) {
            const ushort* pr = opart + (((long)c * 4 + h) * N_TOK + qg) * 64 + (cg & 3) * 16;
            bf16x8 v0 = *(const bf16x8*)(pr);
            bf16x8 v1 = *(const bf16x8*)(pr + 8);
#pragma unroll
            for (int j = 0; j < 8; ++j) {
                a[j] += co[c] * bf2f((ushort)v0[j]);
                a[8 + j] += co[c] * bf2f((ushort)v1[j]);
            }
        }
        int c0 = cg * 16;
#pragma unroll
        for (int g = 0; g < 4; ++g) {
            uint2 u;
            u.x = pkbf(a[g * 4 + 0], a[g * 4 + 1]);
            u.y = pkbf(a[g * 4 + 2], a[g * 4 + 3]);
            *(uint2*)(&mt[q * 256 + ((c0 + g * 4) ^ ((q & 7) * 8))]) = u;
        }
    }
    __syncthreads();
    {
        int w = tid >> 6, lane = tid & 63;
        int fr = lane & 15, kg = lane >> 4;
        f32x4 acc[2] = {};
        for (int k0 = 0; k0 < 256; k0 += 32) {
            bf16x8 a0 = *(const bf16x8*)(WoT + (long)(w * 32 + fr) * 256 + k0 + kg * 8);
            bf16x8 a1 = *(const bf16x8*)(WoT + (long)(w * 32 + 16 + fr) * 256 + k0 + kg * 8);
            bf16x8 b = *(const bf16x8*)(&mt[fr * 256 + ((k0 + kg * 8) ^ ((fr & 7) * 8))]);
            acc[0] = __builtin_amdgcn_mfma_f32_16x16x32_bf16(a0, b, acc[0], 0, 0, 0);
            acc[1] = __builtin_amdgcn_mfma_f32_16x16x32_bf16(a1, b, acc[1], 0, 0, 0);
        }
#pragma unroll
        for (int dt = 0; dt < 2; ++dt)
#pragma unroll
            for (int r = 0; r < 4; ++r)
                PT[(long)(w * 32 + dt * 16 + kg * 4 + r) * N_TOK + q0 + fr] =
                    f2bf(acc[dt][r]);
    }
}

// ---------------- gemm2: part[c] = rpeW[.,Kc] @ PT^T (both bf16, gload_lds) -
__global__ __launch_bounds__(512) void gemm_big2(
    const ushort* __restrict__ A, const ushort* __restrict__ PT,
    float* __restrict__ part) {
    int mt = blockIdx.x, cz = blockIdx.y;
    int tid = threadIdx.x;
    int w = tid >> 6, lane = tid & 63;
    int fr = lane & 15, kg = lane >> 4;
    int lr = lane >> 3, lc = lane & 7;
    int swz = (lc ^ (lr & 7)) * 8;
    int ms = w >> 1, nh = w & 1;
    __shared__ ushort At[2][64 * 64];    // 16 KB
    __shared__ ushort Bt[2][128 * 64];   // 32 KB
    int m0 = mt * 64;
    long kbase = (long)cz * (N_TOK / NC_GEMM);
    int arow = ms * 16 + fr;
    auto stage = [&](int buf, int s) {
        long kc = kbase + s * 64 + swz;
        int rowA = w * 8 + lr;
        __builtin_amdgcn_global_load_lds(
            (const __attribute__((address_space(1))) unsigned int*)(A + (long)(m0 + rowA) * N_TOK + kc),
            (__attribute__((address_space(3))) unsigned int*)(&At[buf][w * 512]), 16, 0, 0);
#pragma unroll
        for (int j = 0; j < 2; ++j) {
            int row = w * 16 + j * 8 + lr;
            __builtin_amdgcn_global_load_lds(
                (const __attribute__((address_space(1))) unsigned int*)(PT + (long)row * N_TOK + kc),
                (__attribute__((address_space(3))) unsigned int*)(&Bt[buf][(w * 2 + j) * 512]), 16, 0, 0);
        }
    };
    f32x4 acc[4] = {};
    stage(0, 0);
    __syncthreads();
    const int NS = (N_TOK / NC_GEMM) / 64;
    for (int s = 0; s < NS; ++s) {
        int buf = s & 1;
        if (s + 1 < NS) stage(buf ^ 1, s + 1);
        __builtin_amdgcn_s_setprio(1);
#pragma unroll
        for (int ks = 0; ks < 2; ++ks) {
            int c = ks * 32 + kg * 8;
            bf16x8 av = *(const bf16x8*)(&At[buf][arow * 64 + (c ^ ((arow & 7) * 8))]);
#pragma unroll
            for (int nf = 0; nf < 4; ++nf) {
                int row = nh * 64 + nf * 16 + fr;
                bf16x8 b = *(const bf16x8*)(&Bt[buf][row * 64 + (c ^ ((row & 7) * 8))]);
                acc[nf] = __builtin_amdgcn_mfma_f32_16x16x32_bf16(av, b, acc[nf], 0, 0, 0);
            }
        }
        __builtin_amdgcn_s_setprio(0);
        __syncthreads();
    }
    float* pb = part + ((long)cz * N_TOK + m0 + ms * 16 + kg * 4) * 128 + nh * 64 + fr;
#pragma unroll
    for (int nf = 0; nf < 4; ++nf)
#pragma unroll
        for (int r = 0; r < 4; ++r)
            pb[(long)r * 128 + nf * 16] = acc[nf][r];
}

// ---------------- megatail: sum parts + bo + x -> LN1 -> FFN -> LN2 -> out --
__global__ __launch_bounds__(256) void megatail(
    const float* __restrict__ gpart, const float* __restrict__ bo,
    const float* __restrict__ x, const float* __restrict__ g1,
    const float* __restrict__ lb1, const ushort* __restrict__ W1T,
    const float* __restrict__ b1, const ushort* __restrict__ W2T,
    const float* __restrict__ b2, const float* __restrict__ g2,
    const float* __restrict__ lb2, float* __restrict__ out) {
    int r0 = blockIdx.x * 16;
    int tid = threadIdx.x;
    int w = tid >> 6, lane = tid & 63;
    int fr = lane & 15, kg = lane >> 4;
    __shared__ float x1f[16][132];
    __shared__ ushort x1b[16][128];
    __shared__ ushort hbuf[16][256];
    __shared__ float otile[16][132];
    int row = tid >> 4, c0 = (tid & 15) * 8;
    {
        float v[8];
        float4 s0 = {0.f, 0.f, 0.f, 0.f}, s1 = {0.f, 0.f, 0.f, 0.f};
#pragma unroll
        for (int c = 0; c < NC_GEMM; ++c) {
            const float* pr = gpart + ((long)c * N_TOK + r0 + row) * 128 + c0;
            float4 a = *(const float4*)(pr);
            float4 b = *(const float4*)(pr + 4);
            s0.x += a.x; s0.y += a.y; s0.z += a.z; s0.w += a.w;
            s1.x += b.x; s1.y += b.y; s1.z += b.z; s1.w += b.w;
        }
        const float* xr = x + (long)(r0 + row) * 128 + c0;
        v[0] = s0.x + bo[c0 + 0] + xr[0];
        v[1] = s0.y + bo[c0 + 1] + xr[1];
        v[2] = s0.z + bo[c0 + 2] + xr[2];
        v[3] = s0.w + bo[c0 + 3] + xr[3];
        v[4] = s1.x + bo[c0 + 4] + xr[4];
        v[5] = s1.y + bo[c0 + 5] + xr[5];
        v[6] = s1.z + bo[c0 + 6] + xr[6];
        v[7] = s1.w + bo[c0 + 7] + xr[7];
        float s = 0.f;
#pragma unroll
        for (int jj = 0; jj < 8; ++jj) s += v[jj];
#pragma unroll
        for (int off = 1; off < 16; off <<= 1) s += __shfl_xor(s, off);
        float mean = s * (1.0f / 128.0f);
        float ss = 0.f;
#pragma unroll
        for (int jj = 0; jj < 8; ++jj) { float d = v[jj] - mean; ss += d * d; }
#pragma unroll
        for (int off = 1; off < 16; off <<= 1) ss += __shfl_xor(ss, off);
        float rstd = rsqrtf(ss * (1.0f / 128.0f) + 1e-5f);
        union { bf16x8 vec; ushort us[8]; } pk8;
#pragma unroll
        for (int jj = 0; jj < 8; ++jj) {
            float y = (v[jj] - mean) * rstd * g1[c0 + jj] + lb1[c0 + jj];
            x1f[row][c0 + jj] = y;
            pk8.us[jj] = f2bf(y);
        }
        *(bf16x8*)(&x1b[row][c0 ^ ((row & 7) * 8)]) = pk8.vec;
    }
    __syncthreads();
    {
        f32x4 a1[4] = {};
#pragma unroll
        for (int ks = 0; ks < 4; ++ks) {
            bf16x8 a = *(const bf16x8*)(&x1b[fr][(ks * 32 + kg * 8) ^ ((fr & 7) * 8)]);
#pragma unroll
            for (int t = 0; t < 4; ++t) {
                bf16x8 b = *(const bf16x8*)(W1T + (long)(w * 64 + t * 16 + fr) * 128 + ks * 32 + kg * 8);
                a1[t] = __builtin_amdgcn_mfma_f32_16x16x32_bf16(a, b, a1[t], 0, 0, 0);
            }
        }
#pragma unroll
        for (int t = 0; t < 4; ++t) {
            int col = w * 64 + t * 16 + fr;
            float bs = b1[col];
#pragma unroll
            for (int r = 0; r < 4; ++r) {
                int rr = kg * 4 + r;
                hbuf[rr][col ^ ((rr & 7) * 8)] = f2bf(fmaxf(a1[t][r] + bs, 0.f));
            }
        }
    }
    __syncthreads();
    {
        f32x4 a2[2] = {};
#pragma unroll
        for (int ks = 0; ks < 8; ++ks) {
            bf16x8 a = *(const bf16x8*)(&hbuf[fr][(ks * 32 + kg * 8) ^ ((fr & 7) * 8)]);
#pragma unroll
            for (int t = 0; t < 2; ++t) {
                bf16x8 b = *(const bf16x8*)(W2T + (long)(w * 32 + t * 16 + fr) * 256 + ks * 32 + kg * 8);
                a2[t] = __builtin_amdgcn_mfma_f32_16x16x32_bf16(a, b, a2[t], 0, 0, 0);
            }
        }
#pragma unroll
        for (int t = 0; t < 2; ++t) {
            int col = w * 32 + t * 16 + fr;
            float bs = b2[col];
#pragma unroll
            for (int r = 0; r < 4; ++r) {
                int rr = kg * 4 + r;
                otile[rr][col] = a2[t][r] + bs + x1f[rr][col];
            }
        }
    }
    __syncthreads();
    {
        float v[8];
        float s = 0.f;
#pragma unroll
        for (int jj = 0; jj < 8; ++jj) { v[jj] = otile[row][c0 + jj]; s += v[jj]; }
#pragma unroll
        for (int off = 1; off < 16; off <<= 1) s += __shfl_xor(s, off);
        float mean = s * (1.0f / 128.0f);
        float ss = 0.f;
#pragma unroll
        for (int jj = 0; jj < 8; ++jj) { float d = v[jj] - mean; ss += d * d; }
#pragma unroll
        for (int off = 1; off < 16; off <<= 1) ss += __shfl_xor(ss, off);
        float rstd = rsqrtf(ss * (1.0f / 128.0f) + 1e-5f);
#pragma unroll
        for (int jj = 0; jj < 8; ++jj) {
            float y = (v[jj] - mean) * rstd * g2[c0 + jj] + lb2[c0 + jj];
            out[(long)(r0 + row) * 128 + c0 + jj] = y;
        }
    }
}

extern "C" void kernel_launch(void* const* d_in, const int* in_sizes, int n_in,
                              void* d_out, int out_size, void* d_ws, size_t ws_size,
                              hipStream_t stream) {
    const float* x     = (const float*)d_in[0];
    const float* rpe   = (const float*)d_in[1];
    const float* Wq    = (const float*)d_in[2];
    const float* bq    = (const float*)d_in[3];
    const float* Wk    = (const float*)d_in[4];
    const float* bk    = (const float*)d_in[5];
    const float* Wv    = (const float*)d_in[6];
    const float* bv    = (const float*)d_in[7];
    const float* rpe_w = (const float*)d_in[8];
    const float* rpe_b = (const float*)d_in[9];
    const float* Wo    = (const float*)d_in[10];
    const float* bo    = (const float*)d_in[11];
    const float* W1    = (const float*)d_in[12];
    const float* b1    = (const float*)d_in[13];
    const float* W2    = (const float*)d_in[14];
    const float* b2    = (const float*)d_in[15];
    const float* g1    = (const float*)d_in[16];
    const float* lb1   = (const float*)d_in[17];
    const float* g2    = (const float*)d_in[18];
    const float* lb2   = (const float*)d_in[19];

    char* wp = (char*)d_ws;
    auto alloc = [&](size_t sz) { char* p = wp; wp += (sz + 255) & ~(size_t)255; return p; };
    ushort* xb    = (ushort*)alloc((size_t)4096 * 128 * 2);
    ushort* WqT   = (ushort*)alloc((size_t)4 * 64 * 128 * 2);
    ushort* WkT   = (ushort*)alloc((size_t)4 * 64 * 128 * 2);
    ushort* WvT   = (ushort*)alloc((size_t)4 * 64 * 128 * 2);
    ushort* WoT   = (ushort*)alloc((size_t)128 * 256 * 2);
    ushort* W1T   = (ushort*)alloc((size_t)256 * 128 * 2);
    ushort* W2T   = (ushort*)alloc((size_t)128 * 256 * 2);
    ushort* qb    = (ushort*)alloc((size_t)4 * 4096 * 64 * 2);
    ushort* kbuf  = (ushort*)alloc((size_t)4 * 4096 * 64 * 2);
    ushort* vT    = (ushort*)alloc((size_t)4 * 64 * 4096 * 2);
    ushort* rpeW  = (ushort*)alloc((size_t)4096 * 4096 * 2);
    ushort* PTb   = (ushort*)alloc((size_t)128 * 4096 * 2);
    ushort* opart = (ushort*)alloc((size_t)NC_ATT * 4 * 4096 * 64 * 2);
    float*  mlprt = (float*)alloc((size_t)NC_ATT * 4 * 4096 * 4);
    float*  gpart = (float*)alloc((size_t)NC_GEMM * 4096 * 128 * 4);

    prep_all<<<1280, 256, 0, stream>>>(x, Wq, Wk, Wv, Wo, W1, W2,
                                       xb, WqT, WkT, WvT, WoT, W1T, W2T);
    fused_rpe_qkv<<<1792, 256, 0, stream>>>(rpe, rpe_w, rpe_b, rpeW,
                                            xb, WqT, WkT, WvT, bq, bk, bv, qb, kbuf, vT);
    fused_rpe_attn<<<2048, 512, 0, stream>>>(rpe, rpe_w, rpe_b, rpeW,
                                             qb, kbuf, vT, opart, mlprt);
    fused_rpe_cw<<<1024, 256, 0, stream>>>(rpe, rpe_w, rpe_b, rpeW,
                                           opart, mlprt, WoT, PTb);
    gemm_big2<<<dim3(64, NC_GEMM), 512, 0, stream>>>(rpeW, PTb, gpart);
    megatail<<<256, 256, 0, stream>>>(gpart, bo, x, g1, lb1, W1T, b1, W2T, b2,
                                      g2, lb2, (float*)d_out);
}